// Round 2
// baseline (13504.919 us; speedup 1.0000x reference)
//
#include <hip/hip_runtime.h>
#include <hip/hip_bf16.h>
#include <math.h>

#define B_ 128
#define S_ 64
#define D_ 512
#define H_ 256
#define SEL_ 128
#define MLPD_ 1024
#define CLS_ 3

__device__ __forceinline__ float sigf(float x) { return 1.f / (1.f + expf(-x)); }

// ---------------- embedding gather: states0[b,s,:] = emb[sent[b,s],:] ----------------
__global__ __launch_bounds__(256) void k_embed(const int* __restrict__ sent,
                                               const float* __restrict__ emb,
                                               float* __restrict__ out) {
    int idx = blockIdx.x * 256 + threadIdx.x;      // float4 index, total B*S*D/4 = 1048576
    int row = idx >> 7;                            // / (D/4)
    int k4  = idx & 127;
    int tok = sent[row];
    ((float4*)out)[idx] = ((const float4*)(emb + (size_t)tok * D_))[k4];
}

// ---------------- reorder comp_W (512x1280): Wr[k][c*5+g] = W[k][g*256+c] ----------------
__global__ __launch_bounds__(256) void k_reorder(const float* __restrict__ W,
                                                 const float* __restrict__ b,
                                                 float* __restrict__ Wr,
                                                 float* __restrict__ br) {
    int idx = blockIdx.x * 256 + threadIdx.x;      // 0 .. 655359
    if (idx < 512 * 1280) {
        int k  = idx / 1280;
        int cg = idx - k * 1280;
        int c  = cg / 5, g = cg - c * 5;
        Wr[idx] = W[k * 1280 + g * 256 + c];
    }
    if (idx < 1280) {
        int c = idx / 5, g = idx - (idx / 5) * 5;
        br[idx] = b[g * 256 + c];
    }
}

// ---------------- selection hidden: hid = tanh([left|right] @ W1 + b1), (M x 1024)@(1024 x 128) ----------------
__global__ __launch_bounds__(256) void k_selhid(const float* __restrict__ states,
                                                const float* __restrict__ W1,
                                                const float* __restrict__ b1,
                                                float* __restrict__ hid,
                                                int N, int M) {
    __shared__ float Xs[32][68];       // [k][m] transposed, padded
    __shared__ float Ws[32][128];
    __shared__ int rowbase[64];
    int tid = threadIdx.x;
    int r0 = blockIdx.x * 64;
    if (tid < 64) {
        int g = r0 + tid;
        rowbase[tid] = (g < M) ? (g + g / N) * 512 : -1;   // (b*L+j)*512, L=N+1
    }
    int ct = tid & 15, rt = tid >> 4;  // cols ct*8..+7, rows rt*4..+3
    float acc[4][8];
#pragma unroll
    for (int r = 0; r < 4; r++)
#pragma unroll
        for (int q = 0; q < 8; q++) acc[r][q] = b1[ct * 8 + q];

    for (int kk = 0; kk < 1024; kk += 32) {
        __syncthreads();
#pragma unroll
        for (int i = 0; i < 2; i++) {
            int idx = tid + i * 256;
            int m = idx >> 3, k4 = (idx & 7) << 2;
            int base = rowbase[m];
            float4 v = {0.f, 0.f, 0.f, 0.f};
            if (base >= 0) v = *(const float4*)(states + base + kk + k4);
            Xs[k4 + 0][m] = v.x; Xs[k4 + 1][m] = v.y; Xs[k4 + 2][m] = v.z; Xs[k4 + 3][m] = v.w;
        }
#pragma unroll
        for (int i = 0; i < 4; i++) {
            int idx = tid + i * 256;
            int k = idx >> 5, c4 = (idx & 31) << 2;
            *(float4*)&Ws[k][c4] = *(const float4*)(W1 + (size_t)(kk + k) * 128 + c4);
        }
        __syncthreads();
#pragma unroll
        for (int k = 0; k < 32; k++) {
            float xv[4];
            *(float4*)xv = *(const float4*)&Xs[k][rt * 4];
            float wv[8];
            *(float4*)&wv[0] = *(const float4*)&Ws[k][ct * 8];
            *(float4*)&wv[4] = *(const float4*)&Ws[k][ct * 8 + 4];
#pragma unroll
            for (int r = 0; r < 4; r++)
#pragma unroll
                for (int q = 0; q < 8; q++) acc[r][q] += xv[r] * wv[q];
        }
    }
#pragma unroll
    for (int r = 0; r < 4; r++) {
        int g = r0 + rt * 4 + r;
        if (g >= M) continue;
#pragma unroll
        for (int q = 0; q < 8; q++) hid[(size_t)g * 128 + ct * 8 + q] = tanhf(acc[r][q]);
    }
}

// ---------------- fused logits + softmax + cumsum + coefficients, one wave per batch ----------------
// logits[j] = dot(hid[b*N+j], W2) + b2 ; then probs/cumsum -> (copy_left, copy_right, select)
__global__ __launch_bounds__(64) void k_coef(const float* __restrict__ hid,
                                             const float* __restrict__ W2,
                                             const float* __restrict__ b2,
                                             float* __restrict__ coef, int N) {
    int b = blockIdx.x, j = threadIdx.x;
    float x = -1e30f;
    if (j < N) {
        const float4* hrow = (const float4*)(hid + ((size_t)b * N + j) * 128);
        const float4* w2v  = (const float4*)W2;
        float acc = 0.f;
#pragma unroll
        for (int k = 0; k < 32; k++) {
            float4 hv = hrow[k];
            float4 wv = w2v[k];
            acc += hv.x * wv.x + hv.y * wv.y + hv.z * wv.z + hv.w * wv.w;
        }
        x = acc + b2[0];
    }
    float mx = x;
#pragma unroll
    for (int o = 32; o >= 1; o >>= 1) mx = fmaxf(mx, __shfl_xor(mx, o));
    float p = (j < N) ? expf(x - mx) : 0.f;
    float tot = p;
#pragma unroll
    for (int o = 32; o >= 1; o >>= 1) tot += __shfl_xor(tot, o);
    float cs = p;
#pragma unroll
    for (int o = 1; o < 64; o <<= 1) {
        float t = __shfl_up(cs, o);
        if (j >= o) cs += t;
    }
    float inv = 1.f / tot;
    float prob = p * inv;
    float csn = cs * inv;
    float cslast = __shfl(csn, N - 1);
    if (j < N) {
        int g = b * N + j;
        coef[g * 3 + 0] = cslast - csn;   // copy_left
        coef[g * 3 + 1] = csn - prob;     // copy_right
        coef[g * 3 + 2] = prob;           // select
    }
}

// ---------------- fused gates GEMM + treeLSTM + weighted combine -> next states ----------------
// (M x 512) @ Wr(512 x 1280 reordered), epilogue computes h,c and states_out = cl*L + cr*R + sel*comp
__global__ __launch_bounds__(256) void k_compose(const float* __restrict__ states,
                                                 const float* __restrict__ Wr,
                                                 const float* __restrict__ br,
                                                 const float* __restrict__ coef,
                                                 float* __restrict__ out,
                                                 int N, int M) {
    __shared__ float Xs[32][68];
    __shared__ float Ws[32][160];
    __shared__ int rowbase[64];
    int tid = threadIdx.x;
    int r0 = blockIdx.x * 64;
    int c0 = blockIdx.y * 32;           // comp-column base (of 256)
    if (tid < 64) {
        int g = r0 + tid;
        rowbase[tid] = (g < M) ? (g + g / N) * 512 : -1;
    }
    int ct = tid & 7, rt = tid >> 3;    // rt 0..31 -> rows rt*2..+1 ; ct -> comp cols c0+ct*4..+3
    float acc[2][20];
#pragma unroll
    for (int r = 0; r < 2; r++)
#pragma unroll
        for (int q = 0; q < 20; q++) acc[r][q] = br[c0 * 5 + ct * 20 + q];

    for (int kk = 0; kk < 512; kk += 32) {
        __syncthreads();
        int koff = (kk < 256) ? kk : kk + 256;   // k<256: left h ; k>=256: right h (= base+512+(k-256))
#pragma unroll
        for (int i = 0; i < 2; i++) {
            int idx = tid + i * 256;
            int m = idx >> 3, k4 = (idx & 7) << 2;
            int base = rowbase[m];
            float4 v = {0.f, 0.f, 0.f, 0.f};
            if (base >= 0) v = *(const float4*)(states + base + koff + k4);
            Xs[k4 + 0][m] = v.x; Xs[k4 + 1][m] = v.y; Xs[k4 + 2][m] = v.z; Xs[k4 + 3][m] = v.w;
        }
#pragma unroll
        for (int i = 0; i < 5; i++) {
            int idx = tid + i * 256;            // 0..1279
            int k = idx / 40;
            int c4 = (idx - k * 40) << 2;
            *(float4*)&Ws[k][c4] = *(const float4*)(Wr + (size_t)(kk + k) * 1280 + c0 * 5 + c4);
        }
        __syncthreads();
#pragma unroll
        for (int k = 0; k < 32; k++) {
            float xv0 = Xs[k][rt * 2], xv1 = Xs[k][rt * 2 + 1];
            float wv[20];
#pragma unroll
            for (int i = 0; i < 5; i++) *(float4*)&wv[i * 4] = *(const float4*)&Ws[k][ct * 20 + i * 4];
#pragma unroll
            for (int q = 0; q < 20; q++) { acc[0][q] += xv0 * wv[q]; acc[1][q] += xv1 * wv[q]; }
        }
    }
#pragma unroll
    for (int r = 0; r < 2; r++) {
        int m = rt * 2 + r;
        int g = r0 + m;
        if (g >= M) continue;
        int base = rowbase[m];
        float cl = coef[g * 3 + 0], cr = coef[g * 3 + 1], sl = coef[g * 3 + 2];
#pragma unroll
        for (int cc = 0; cc < 4; cc++) {
            int c = c0 + ct * 4 + cc;
            float gi = acc[r][cc * 5 + 0];
            float gfl = acc[r][cc * 5 + 1];
            float gfr = acc[r][cc * 5 + 2];
            float gu = acc[r][cc * 5 + 3];
            float go = acc[r][cc * 5 + 4];
            float h_l = states[base + c],       c_l = states[base + 256 + c];
            float h_r = states[base + 512 + c], c_r = states[base + 768 + c];
            float cn = sigf(gfl) * c_l + sigf(gfr) * c_r + sigf(gi) * tanhf(gu);
            float hn = sigf(go) * tanhf(cn);
            out[(size_t)g * 512 + c]       = cl * h_l + cr * h_r + sl * hn;
            out[(size_t)g * 512 + 256 + c] = cl * c_l + cr * c_r + sl * cn;
        }
    }
}

// ---------------- generic small GEMM with optional ReLU (for final MLP) ----------------
template <int ACT>
__global__ __launch_bounds__(256) void k_gemm(const float* __restrict__ A,
                                              const float* __restrict__ W,
                                              const float* __restrict__ bias,
                                              float* __restrict__ C,
                                              int M, int K, int Nc) {
    __shared__ float Xs[32][36];
    __shared__ float Ws[32][64];
    int tid = threadIdx.x;
    int r0 = blockIdx.x * 32, c0 = blockIdx.y * 64;
    int ct = tid & 15, rt = tid >> 4;   // cols ct*4..+3, rows rt*2..+1
    float acc[2][4];
#pragma unroll
    for (int r = 0; r < 2; r++)
#pragma unroll
        for (int q = 0; q < 4; q++) {
            int c = c0 + ct * 4 + q;
            acc[r][q] = (c < Nc) ? bias[c] : 0.f;
        }
    for (int kk = 0; kk < K; kk += 32) {
        __syncthreads();
        {
            int m = tid >> 3, k4 = (tid & 7) << 2;
            float4 v = {0.f, 0.f, 0.f, 0.f};
            if (r0 + m < M) v = *(const float4*)(A + (size_t)(r0 + m) * K + kk + k4);
            Xs[k4 + 0][m] = v.x; Xs[k4 + 1][m] = v.y; Xs[k4 + 2][m] = v.z; Xs[k4 + 3][m] = v.w;
        }
#pragma unroll
        for (int i = 0; i < 2; i++) {
            int idx = tid + i * 256;
            int k = idx >> 4, c4 = (idx & 15) << 2;
            int c = c0 + c4;
            float4 v = {0.f, 0.f, 0.f, 0.f};
            if (c + 3 < Nc) {
                v = *(const float4*)(W + (size_t)(kk + k) * Nc + c);
            } else {
                float tmp[4] = {0.f, 0.f, 0.f, 0.f};
                for (int j = 0; j < 4; j++)
                    if (c + j < Nc) tmp[j] = W[(size_t)(kk + k) * Nc + c + j];
                v = *(float4*)tmp;
            }
            *(float4*)&Ws[k][c4] = v;
        }
        __syncthreads();
#pragma unroll
        for (int k = 0; k < 32; k++) {
            float x0 = Xs[k][rt * 2], x1 = Xs[k][rt * 2 + 1];
            float wv[4];
            *(float4*)wv = *(const float4*)&Ws[k][ct * 4];
#pragma unroll
            for (int q = 0; q < 4; q++) { acc[0][q] += x0 * wv[q]; acc[1][q] += x1 * wv[q]; }
        }
    }
#pragma unroll
    for (int r = 0; r < 2; r++) {
        int g = r0 + rt * 2 + r;
        if (g >= M) continue;
#pragma unroll
        for (int q = 0; q < 4; q++) {
            int c = c0 + ct * 4 + q;
            if (c >= Nc) continue;
            float v = acc[r][q];
            if (ACT == 1) v = fmaxf(v, 0.f);
            C[(size_t)g * Nc + c] = v;
        }
    }
}

extern "C" void kernel_launch(void* const* d_in, const int* in_sizes, int n_in,
                              void* d_out, int out_size, void* d_ws, size_t ws_size,
                              hipStream_t stream) {
    const int*   sent     = (const int*)d_in[0];
    // d_in[1] transitions: unused by reference
    const float* emb      = (const float*)d_in[2];
    const float* comp_W   = (const float*)d_in[3];
    const float* comp_b   = (const float*)d_in[4];
    const float* sel_W1   = (const float*)d_in[5];
    const float* sel_b1   = (const float*)d_in[6];
    const float* sel_W2   = (const float*)d_in[7];
    const float* sel_b2   = (const float*)d_in[8];
    const float* mlp_W0   = (const float*)d_in[9];
    const float* mlp_b0   = (const float*)d_in[10];
    const float* mlp_W1   = (const float*)d_in[11];
    const float* mlp_b1   = (const float*)d_in[12];
    const float* mlp_Wout = (const float*)d_in[13];
    const float* mlp_bout = (const float*)d_in[14];
    float* outp = (float*)d_out;

    char* p = (char*)d_ws;
    float* st0    = (float*)p; p += (size_t)B_ * S_ * D_ * 4;
    float* st1    = (float*)p; p += (size_t)B_ * S_ * D_ * 4;
    float* Wr     = (float*)p; p += (size_t)512 * 1280 * 4;
    float* brr    = (float*)p; p += 1280 * 4;
    float* hid    = (float*)p; p += (size_t)B_ * 63 * SEL_ * 4;
    float* coef   = (float*)p; p += (size_t)B_ * 63 * 3 * 4;
    float* h1     = (float*)p; p += (size_t)B_ * MLPD_ * 4;
    float* h2     = (float*)p; p += (size_t)B_ * MLPD_ * 4;

    k_embed<<<dim3(4096), dim3(256), 0, stream>>>(sent, emb, st0);
    k_reorder<<<dim3(2560), dim3(256), 0, stream>>>(comp_W, comp_b, Wr, brr);

    float* src = st0;
    float* dst = st1;
    for (int L = S_; L >= 2; --L) {
        int N = L - 1;
        int M = B_ * N;
        int mb = (M + 63) / 64;
        k_selhid<<<dim3(mb), dim3(256), 0, stream>>>(src, sel_W1, sel_b1, hid, N, M);
        k_coef<<<dim3(B_), dim3(64), 0, stream>>>(hid, sel_W2, sel_b2, coef, N);
        k_compose<<<dim3(mb, 8), dim3(256), 0, stream>>>(src, Wr, brr, coef, dst, N, M);
        float* t = src; src = dst; dst = t;
    }

    k_gemm<1><<<dim3(4, 16), dim3(256), 0, stream>>>(src, mlp_W0, mlp_b0, h1, B_, 512, MLPD_);
    k_gemm<1><<<dim3(4, 16), dim3(256), 0, stream>>>(h1, mlp_W1, mlp_b1, h2, B_, 1024, MLPD_);
    k_gemm<0><<<dim3(4, 1), dim3(256), 0, stream>>>(h2, mlp_Wout, mlp_bout, outp, B_, 1024, CLS_);
}

// Round 4
// 7244.843 us; speedup vs baseline: 1.8641x; 1.8641x over previous
//
#include <hip/hip_runtime.h>
#include <hip/hip_bf16.h>
#include <math.h>

#define B_ 128
#define S_ 64
#define D_ 512
#define H_ 256
#define SEL_ 128
#define MLPD_ 1024
#define CLS_ 3

typedef __attribute__((ext_vector_type(8))) short bf16x8;
typedef __attribute__((ext_vector_type(4))) float f32x4;

__device__ __forceinline__ float sigf(float x) { return 1.f / (1.f + expf(-x)); }

// fp32 -> bf16 round-to-nearest-even (bit trick; no inf/nan in this workload)
__device__ __forceinline__ ushort bf16r(float x) {
    uint u = __float_as_uint(x);
    return (ushort)((u + 0x7fffu + ((u >> 16) & 1u)) >> 16);
}
__device__ __forceinline__ float bf2f(ushort h) { return __uint_as_float(((uint)h) << 16); }

// ---------------- embedding gather + bf16 hi/lo split (state := hi+lo) ----------------
__global__ __launch_bounds__(256) void k_embed(const int* __restrict__ sent,
                                               const float* __restrict__ emb,
                                               ushort* __restrict__ oh,
                                               ushort* __restrict__ ol) {
    int idx = blockIdx.x * 256 + threadIdx.x;      // B*S*D/4 float4 slots
    int row = idx >> 7;
    int k4 = (idx & 127) << 2;
    int tok = sent[row];
    float4 v = *(const float4*)(emb + (size_t)tok * D_ + k4);
    ushort4 h, l;
    h.x = bf16r(v.x); l.x = bf16r(v.x - bf2f(h.x));
    h.y = bf16r(v.y); l.y = bf16r(v.y - bf2f(h.y));
    h.z = bf16r(v.z); l.z = bf16r(v.z - bf2f(h.z));
    h.w = bf16r(v.w); l.w = bf16r(v.w - bf2f(h.w));
    *(ushort4*)(oh + (size_t)row * D_ + k4) = h;
    *(ushort4*)(ol + (size_t)row * D_ + k4) = l;
}

// ---------------- transpose + split: dst[n][k] = src[k][n], K,N multiples of 64 ----------------
__global__ __launch_bounds__(256) void k_tsplit(const float* __restrict__ src,
                                                ushort* __restrict__ dh,
                                                ushort* __restrict__ dl,
                                                int K, int N) {
    __shared__ float t[64][65];
    int n0 = blockIdx.x * 64, k0 = blockIdx.y * 64;
    int tx = threadIdx.x & 63, ty = threadIdx.x >> 6;
    for (int i = ty; i < 64; i += 4)
        t[i][tx] = src[(size_t)(k0 + i) * N + n0 + tx];
    __syncthreads();
    for (int i = ty; i < 64; i += 4) {
        float v = t[tx][i];
        ushort h = bf16r(v);
        size_t o = (size_t)(n0 + i) * K + k0 + tx;
        dh[o] = h;
        dl[o] = bf16r(v - bf2f(h));
    }
}

// ---------------- selection hidden via MFMA (bf16x2 split, 3-term) ----------------
// hid[g][c] = tanh(sel_in[g] . W1[:,c] + b1[c]); sel_in row g = states[(g+g/N)*512 .. +1024)
__global__ __launch_bounds__(256) void k_selhid(const ushort* __restrict__ sh,
                                                const ushort* __restrict__ sl,
                                                const ushort* __restrict__ w1h,
                                                const ushort* __restrict__ w1l,
                                                const float* __restrict__ b1,
                                                float* __restrict__ hid,
                                                int N, int M, int cdiv) {
    int tid = threadIdx.x, l = tid & 63, wid = tid >> 6;
    int wm = wid >> 1, wn = wid & 1;
    int r0 = blockIdx.x * 64 + wm * 32;
    int c0 = blockIdx.y * 64 + wn * 32;
    int lr = l & 15, lk = (l >> 4) << 3;

    size_t ab[2], bb[2];
    float bias[2];
#pragma unroll
    for (int t = 0; t < 2; t++) {
        int g = r0 + t * 16 + lr;
        int q = (int)(((long long)g * cdiv) >> 20);      // g / N
        ab[t] = (size_t)(g + q) * 512;
        int c = c0 + t * 16 + lr;
        bb[t] = (size_t)c * 1024;
        bias[t] = b1[c];
    }
    f32x4 z = {0.f, 0.f, 0.f, 0.f};
    f32x4 acc[2][2] = {{z, z}, {z, z}};

    for (int kk = 0; kk < 1024; kk += 32) {
        bf16x8 ah[2], al[2], bh[2], bl[2];
#pragma unroll
        for (int t = 0; t < 2; t++) {
            ah[t] = *(const bf16x8*)(sh + ab[t] + kk + lk);
            al[t] = *(const bf16x8*)(sl + ab[t] + kk + lk);
            bh[t] = *(const bf16x8*)(w1h + bb[t] + kk + lk);
            bl[t] = *(const bf16x8*)(w1l + bb[t] + kk + lk);
        }
#pragma unroll
        for (int ti = 0; ti < 2; ti++)
#pragma unroll
            for (int tj = 0; tj < 2; tj++) {
                acc[ti][tj] = __builtin_amdgcn_mfma_f32_16x16x32_bf16(ah[ti], bh[tj], acc[ti][tj], 0, 0, 0);
                acc[ti][tj] = __builtin_amdgcn_mfma_f32_16x16x32_bf16(ah[ti], bl[tj], acc[ti][tj], 0, 0, 0);
                acc[ti][tj] = __builtin_amdgcn_mfma_f32_16x16x32_bf16(al[ti], bh[tj], acc[ti][tj], 0, 0, 0);
            }
    }
#pragma unroll
    for (int ti = 0; ti < 2; ti++)
#pragma unroll
        for (int tj = 0; tj < 2; tj++)
#pragma unroll
            for (int r = 0; r < 4; r++) {
                int g = r0 + ti * 16 + ((l >> 4) << 2) + r;   // D: row=(lane>>4)*4+reg
                int c = c0 + tj * 16 + lr;                    //    col=lane&15
                hid[(size_t)g * 128 + c] = tanhf(acc[ti][tj][r] + bias[tj]);
            }
}

// ---------------- fused logits + softmax + cumsum -> coefficients, one wave per batch ----------------
__global__ __launch_bounds__(64) void k_coef(const float* __restrict__ hid,
                                             const float* __restrict__ W2,
                                             const float* __restrict__ b2,
                                             float* __restrict__ coef, int N) {
    int b = blockIdx.x, j = threadIdx.x;
    float x = -1e30f;
    if (j < N) {
        const float4* hrow = (const float4*)(hid + ((size_t)b * N + j) * 128);
        const float4* w2v = (const float4*)W2;
        float acc = 0.f;
#pragma unroll
        for (int k = 0; k < 32; k++) {
            float4 hv = hrow[k];
            float4 wv = w2v[k];
            acc += hv.x * wv.x + hv.y * wv.y + hv.z * wv.z + hv.w * wv.w;
        }
        x = acc + b2[0];
    }
    float mx = x;
#pragma unroll
    for (int o = 32; o >= 1; o >>= 1) mx = fmaxf(mx, __shfl_xor(mx, o));
    float p = (j < N) ? expf(x - mx) : 0.f;
    float tot = p;
#pragma unroll
    for (int o = 32; o >= 1; o >>= 1) tot += __shfl_xor(tot, o);
    float cs = p;
#pragma unroll
    for (int o = 1; o < 64; o <<= 1) {
        float t = __shfl_up(cs, o);
        if (j >= o) cs += t;
    }
    float inv = 1.f / tot;
    float prob = p * inv;
    float csn = cs * inv;
    float cslast = __shfl(csn, N - 1);
    if (j < N) {
        int g = b * N + j;
        coef[g * 3 + 0] = cslast - csn;   // copy_left
        coef[g * 3 + 1] = csn - prob;     // copy_right
        coef[g * 3 + 2] = prob;           // select
    }
}

// ---------------- fused gates GEMM (MFMA bf16x2) + treeLSTM + combine -> next states ----------------
// A row g = [h_l | h_r] from state row base; B = comp_W natural cols (gate strips g*256+c), pre-transposed.
// States live as hi/lo bf16 planes; fp32 value := hi+lo. Final layer (N==1) also writes fp32 root.
__global__ __launch_bounds__(256) void k_compose(const ushort* __restrict__ sh,
                                                 const ushort* __restrict__ sl,
                                                 const ushort* __restrict__ wth,
                                                 const ushort* __restrict__ wtl,
                                                 const float* __restrict__ cbias,
                                                 const float* __restrict__ coef,
                                                 ushort* __restrict__ dh,
                                                 ushort* __restrict__ dl,
                                                 float* __restrict__ root,
                                                 int N, int M, int cdiv) {
    int tid = threadIdx.x, l = tid & 63, wid = tid >> 6;
    int wm = wid >> 1, wn = wid & 1;
    int r0 = blockIdx.x * 64 + wm * 32;
    int cb = blockIdx.y * 32 + wn * 16;      // comp-column tile base (of 256)
    int lr = l & 15, lk = (l >> 4) << 3;

    size_t ab[2];
#pragma unroll
    for (int t = 0; t < 2; t++) {
        int g = r0 + t * 16 + lr;
        int q = (int)(((long long)g * cdiv) >> 20);
        ab[t] = (size_t)(g + q) * 512;
    }
    size_t bb[5];
    float bias[5];
#pragma unroll
    for (int gt = 0; gt < 5; gt++) {
        int c = gt * 256 + cb + lr;
        bb[gt] = (size_t)c * 512;
        bias[gt] = cbias[c];
    }
    f32x4 z = {0.f, 0.f, 0.f, 0.f};
    f32x4 acc[2][5] = {{z, z, z, z, z}, {z, z, z, z, z}};

    for (int kk = 0; kk < 512; kk += 32) {
        int koff = (kk < 256) ? kk : kk + 256;   // k<256: left h ; k>=256: right h
        bf16x8 ah[2], al[2];
#pragma unroll
        for (int t = 0; t < 2; t++) {
            ah[t] = *(const bf16x8*)(sh + ab[t] + koff + lk);
            al[t] = *(const bf16x8*)(sl + ab[t] + koff + lk);
        }
#pragma unroll
        for (int gt = 0; gt < 5; gt++) {
            bf16x8 bh = *(const bf16x8*)(wth + bb[gt] + kk + lk);
            bf16x8 bl = *(const bf16x8*)(wtl + bb[gt] + kk + lk);
#pragma unroll
            for (int t = 0; t < 2; t++) {
                acc[t][gt] = __builtin_amdgcn_mfma_f32_16x16x32_bf16(ah[t], bh, acc[t][gt], 0, 0, 0);
                acc[t][gt] = __builtin_amdgcn_mfma_f32_16x16x32_bf16(ah[t], bl, acc[t][gt], 0, 0, 0);
                acc[t][gt] = __builtin_amdgcn_mfma_f32_16x16x32_bf16(al[t], bh, acc[t][gt], 0, 0, 0);
            }
        }
    }

#pragma unroll
    for (int t = 0; t < 2; t++)
#pragma unroll
        for (int r = 0; r < 4; r++) {
            int m = r0 + t * 16 + ((l >> 4) << 2) + r;
            int q = (int)(((long long)m * cdiv) >> 20);
            size_t sb = (size_t)(m + q) * 512;
            int c = cb + lr;
            float cl = coef[m * 3 + 0], cr = coef[m * 3 + 1], sel = coef[m * 3 + 2];
            float h_l = bf2f(sh[sb + c])       + bf2f(sl[sb + c]);
            float c_l = bf2f(sh[sb + 256 + c]) + bf2f(sl[sb + 256 + c]);
            float h_r = bf2f(sh[sb + 512 + c]) + bf2f(sl[sb + 512 + c]);
            float c_r = bf2f(sh[sb + 768 + c]) + bf2f(sl[sb + 768 + c]);
            float gi  = acc[t][0][r] + bias[0];
            float gfl = acc[t][1][r] + bias[1];
            float gfr = acc[t][2][r] + bias[2];
            float gu  = acc[t][3][r] + bias[3];
            float go  = acc[t][4][r] + bias[4];
            float cn = sigf(gfl) * c_l + sigf(gfr) * c_r + sigf(gi) * tanhf(gu);
            float hn = sigf(go) * tanhf(cn);
            float oh = cl * h_l + cr * h_r + sel * hn;
            float oc = cl * c_l + cr * c_r + sel * cn;
            size_t ob = (size_t)m * 512 + c;
            ushort hh = bf16r(oh);
            dh[ob] = hh;
            dl[ob] = bf16r(oh - bf2f(hh));
            ushort hc = bf16r(oc);
            dh[ob + 256] = hc;
            dl[ob + 256] = bf16r(oc - bf2f(hc));
            if (N == 1) {                       // final layer: fp32 root for the MLP head
                root[ob] = oh;
                root[ob + 256] = oc;
            }
        }
}

// ---------------- generic small fp32 GEMM with optional ReLU (final MLP) ----------------
template <int ACT>
__global__ __launch_bounds__(256) void k_gemm(const float* __restrict__ A,
                                              const float* __restrict__ W,
                                              const float* __restrict__ bias,
                                              float* __restrict__ C,
                                              int M, int K, int Nc) {
    __shared__ float Xs[32][36];
    __shared__ float Ws[32][64];
    int tid = threadIdx.x;
    int r0 = blockIdx.x * 32, c0 = blockIdx.y * 64;
    int ct = tid & 15, rt = tid >> 4;
    float acc[2][4];
#pragma unroll
    for (int r = 0; r < 2; r++)
#pragma unroll
        for (int q = 0; q < 4; q++) {
            int c = c0 + ct * 4 + q;
            acc[r][q] = (c < Nc) ? bias[c] : 0.f;
        }
    for (int kk = 0; kk < K; kk += 32) {
        __syncthreads();
        {
            int m = tid >> 3, k4 = (tid & 7) << 2;
            float4 v = {0.f, 0.f, 0.f, 0.f};
            if (r0 + m < M) v = *(const float4*)(A + (size_t)(r0 + m) * K + kk + k4);
            Xs[k4 + 0][m] = v.x; Xs[k4 + 1][m] = v.y; Xs[k4 + 2][m] = v.z; Xs[k4 + 3][m] = v.w;
        }
#pragma unroll
        for (int i = 0; i < 2; i++) {
            int idx = tid + i * 256;
            int k = idx >> 4, c4 = (idx & 15) << 2;
            int c = c0 + c4;
            float4 v = {0.f, 0.f, 0.f, 0.f};
            if (c + 3 < Nc) {
                v = *(const float4*)(W + (size_t)(kk + k) * Nc + c);
            } else {
                float tmp[4] = {0.f, 0.f, 0.f, 0.f};
                for (int j = 0; j < 4; j++)
                    if (c + j < Nc) tmp[j] = W[(size_t)(kk + k) * Nc + c + j];
                v = *(float4*)tmp;
            }
            *(float4*)&Ws[k][c4] = v;
        }
        __syncthreads();
#pragma unroll
        for (int k = 0; k < 32; k++) {
            float x0 = Xs[k][rt * 2], x1 = Xs[k][rt * 2 + 1];
            float wv[4];
            *(float4*)wv = *(const float4*)&Ws[k][ct * 4];
#pragma unroll
            for (int q = 0; q < 4; q++) { acc[0][q] += x0 * wv[q]; acc[1][q] += x1 * wv[q]; }
        }
    }
#pragma unroll
    for (int r = 0; r < 2; r++) {
        int g = r0 + rt * 2 + r;
        if (g >= M) continue;
#pragma unroll
        for (int q = 0; q < 4; q++) {
            int c = c0 + ct * 4 + q;
            if (c >= Nc) continue;
            float v = acc[r][q];
            if (ACT == 1) v = fmaxf(v, 0.f);
            C[(size_t)g * Nc + c] = v;
        }
    }
}

extern "C" void kernel_launch(void* const* d_in, const int* in_sizes, int n_in,
                              void* d_out, int out_size, void* d_ws, size_t ws_size,
                              hipStream_t stream) {
    const int*   sent     = (const int*)d_in[0];
    // d_in[1] transitions: unused by reference
    const float* emb      = (const float*)d_in[2];
    const float* comp_W   = (const float*)d_in[3];
    const float* comp_b   = (const float*)d_in[4];
    const float* sel_W1   = (const float*)d_in[5];
    const float* sel_b1   = (const float*)d_in[6];
    const float* sel_W2   = (const float*)d_in[7];
    const float* sel_b2   = (const float*)d_in[8];
    const float* mlp_W0   = (const float*)d_in[9];
    const float* mlp_b0   = (const float*)d_in[10];
    const float* mlp_W1   = (const float*)d_in[11];
    const float* mlp_b1   = (const float*)d_in[12];
    const float* mlp_Wout = (const float*)d_in[13];
    const float* mlp_bout = (const float*)d_in[14];
    float* outp = (float*)d_out;

    char* p = (char*)d_ws;
    ushort* sh0  = (ushort*)p; p += (size_t)B_ * S_ * D_ * 2;
    ushort* sl0  = (ushort*)p; p += (size_t)B_ * S_ * D_ * 2;
    ushort* sh1  = (ushort*)p; p += (size_t)B_ * S_ * D_ * 2;
    ushort* sl1  = (ushort*)p; p += (size_t)B_ * S_ * D_ * 2;
    ushort* wth  = (ushort*)p; p += (size_t)1280 * 512 * 2;
    ushort* wtl  = (ushort*)p; p += (size_t)1280 * 512 * 2;
    ushort* w1th = (ushort*)p; p += (size_t)128 * 1024 * 2;
    ushort* w1tl = (ushort*)p; p += (size_t)128 * 1024 * 2;
    float*  hid  = (float*)p;  p += (size_t)B_ * 63 * SEL_ * 4;
    float*  coef = (float*)p;  p += (size_t)B_ * 63 * 3 * 4;
    float*  root = (float*)p;  p += (size_t)B_ * D_ * 4;
    float*  h1   = (float*)p;  p += (size_t)B_ * MLPD_ * 4;
    float*  h2   = (float*)p;  p += (size_t)B_ * MLPD_ * 4;

    k_embed<<<dim3(4096), dim3(256), 0, stream>>>(sent, emb, sh0, sl0);
    k_tsplit<<<dim3(20, 8), dim3(256), 0, stream>>>(comp_W, wth, wtl, 512, 1280);
    k_tsplit<<<dim3(2, 16), dim3(256), 0, stream>>>(sel_W1, w1th, w1tl, 1024, 128);

    ushort* shs = sh0; ushort* sls = sl0;
    ushort* shd = sh1; ushort* sld = sl1;
    for (int L = S_; L >= 2; --L) {
        int N = L - 1;
        int M = B_ * N;
        int cdiv = (1048576 + N - 1) / N;
        k_selhid<<<dim3(M / 64, 2), dim3(256), 0, stream>>>(shs, sls, w1th, w1tl, sel_b1, hid, N, M, cdiv);
        k_coef<<<dim3(B_), dim3(64), 0, stream>>>(hid, sel_W2, sel_b2, coef, N);
        k_compose<<<dim3(M / 64, 8), dim3(256), 0, stream>>>(shs, sls, wth, wtl, comp_b, coef,
                                                             shd, sld, root, N, M, cdiv);
        ushort* th = shs; shs = shd; shd = th;
        ushort* tl = sls; sls = sld; sld = tl;
    }

    k_gemm<1><<<dim3(4, 16), dim3(256), 0, stream>>>(root, mlp_W0, mlp_b0, h1, B_, 512, MLPD_);
    k_gemm<1><<<dim3(4, 16), dim3(256), 0, stream>>>(h1, mlp_W1, mlp_b1, h2, B_, 1024, MLPD_);
    k_gemm<0><<<dim3(4, 1), dim3(256), 0, stream>>>(h2, mlp_Wout, mlp_bout, outp, B_, 1024, CLS_);
}

// Round 5
// 6941.858 us; speedup vs baseline: 1.9454x; 1.0436x over previous
//
#include <hip/hip_runtime.h>
#include <hip/hip_bf16.h>
#include <math.h>

#define B_ 128
#define S_ 64
#define D_ 512
#define H_ 256
#define SEL_ 128
#define MLPD_ 1024
#define CLS_ 3

typedef __attribute__((ext_vector_type(8))) short bf16x8;
typedef __attribute__((ext_vector_type(4))) float f32x4;

__device__ __forceinline__ float sigf(float x) { return 1.f / (1.f + expf(-x)); }

// fp32 -> bf16 round-to-nearest-even (bit trick; no inf/nan in this workload)
__device__ __forceinline__ ushort bf16r(float x) {
    uint u = __float_as_uint(x);
    return (ushort)((u + 0x7fffu + ((u >> 16) & 1u)) >> 16);
}
__device__ __forceinline__ float bf2f(ushort h) { return __uint_as_float(((uint)h) << 16); }

// ---------------- embedding gather + bf16 hi/lo split (state := hi+lo) ----------------
__global__ __launch_bounds__(256) void k_embed(const int* __restrict__ sent,
                                               const float* __restrict__ emb,
                                               ushort* __restrict__ oh,
                                               ushort* __restrict__ ol) {
    int idx = blockIdx.x * 256 + threadIdx.x;      // B*S*D/4 float4 slots
    int row = idx >> 7;
    int k4 = (idx & 127) << 2;
    int tok = sent[row];
    float4 v = *(const float4*)(emb + (size_t)tok * D_ + k4);
    ushort4 h, l;
    h.x = bf16r(v.x); l.x = bf16r(v.x - bf2f(h.x));
    h.y = bf16r(v.y); l.y = bf16r(v.y - bf2f(h.y));
    h.z = bf16r(v.z); l.z = bf16r(v.z - bf2f(h.z));
    h.w = bf16r(v.w); l.w = bf16r(v.w - bf2f(h.w));
    *(ushort4*)(oh + (size_t)row * D_ + k4) = h;
    *(ushort4*)(ol + (size_t)row * D_ + k4) = l;
}

// ---------------- transpose + split: dst[n][k] = src[k][n], K,N multiples of 64 ----------------
__global__ __launch_bounds__(256) void k_tsplit(const float* __restrict__ src,
                                                ushort* __restrict__ dh,
                                                ushort* __restrict__ dl,
                                                int K, int N) {
    __shared__ float t[64][65];
    int n0 = blockIdx.x * 64, k0 = blockIdx.y * 64;
    int tx = threadIdx.x & 63, ty = threadIdx.x >> 6;
    for (int i = ty; i < 64; i += 4)
        t[i][tx] = src[(size_t)(k0 + i) * N + n0 + tx];
    __syncthreads();
    for (int i = ty; i < 64; i += 4) {
        float v = t[tx][i];
        ushort h = bf16r(v);
        size_t o = (size_t)(n0 + i) * K + k0 + tx;
        dh[o] = h;
        dl[o] = bf16r(v - bf2f(h));
    }
}

// ---------------- selection hidden via MFMA (bf16x2 split, 3-term), reg-double-buffered ----------------
// grid (2, M/64): consecutive blocks share A rows -> L2 locality.
__global__ __launch_bounds__(256) void k_selhid(const ushort* __restrict__ sh,
                                                const ushort* __restrict__ sl,
                                                const ushort* __restrict__ w1h,
                                                const ushort* __restrict__ w1l,
                                                const float* __restrict__ b1,
                                                float* __restrict__ hid,
                                                int N, int M, int cdiv) {
    int tid = threadIdx.x, l = tid & 63, wid = tid >> 6;
    int wm = wid >> 1, wn = wid & 1;
    int r0 = blockIdx.y * 64 + wm * 32;
    int c0 = blockIdx.x * 64 + wn * 32;
    int lr = l & 15, lk = (l >> 4) << 3;

    int ab[2], bb[2];
    float bias[2];
#pragma unroll
    for (int t = 0; t < 2; t++) {
        int g = r0 + t * 16 + lr;
        int q = (int)(((long long)g * cdiv) >> 20);      // g / N
        ab[t] = (g + q) * 512;
        int c = c0 + t * 16 + lr;
        bb[t] = c * 1024;
        bias[t] = b1[c];
    }
    f32x4 z = {0.f, 0.f, 0.f, 0.f};
    f32x4 acc[2][2] = {{z, z}, {z, z}};
    bf16x8 ah[2][2], al[2][2], bh[2][2], bl[2][2];

#define SLOAD(buf, ks) do {                                              \
        int kk_ = (ks) * 32;                                             \
        _Pragma("unroll")                                                \
        for (int t = 0; t < 2; t++) {                                    \
            ah[buf][t] = *(const bf16x8*)(sh + ab[t] + kk_ + lk);        \
            al[buf][t] = *(const bf16x8*)(sl + ab[t] + kk_ + lk);       \
            bh[buf][t] = *(const bf16x8*)(w1h + bb[t] + kk_ + lk);      \
            bl[buf][t] = *(const bf16x8*)(w1l + bb[t] + kk_ + lk);      \
        }                                                                \
    } while (0)

#define SMFMA(buf) do {                                                  \
        _Pragma("unroll")                                                \
        for (int ti = 0; ti < 2; ti++)                                   \
            _Pragma("unroll")                                            \
            for (int tj = 0; tj < 2; tj++) {                             \
                acc[ti][tj] = __builtin_amdgcn_mfma_f32_16x16x32_bf16(ah[buf][ti], bh[buf][tj], acc[ti][tj], 0, 0, 0); \
                acc[ti][tj] = __builtin_amdgcn_mfma_f32_16x16x32_bf16(ah[buf][ti], bl[buf][tj], acc[ti][tj], 0, 0, 0); \
                acc[ti][tj] = __builtin_amdgcn_mfma_f32_16x16x32_bf16(al[buf][ti], bh[buf][tj], acc[ti][tj], 0, 0, 0); \
            }                                                            \
    } while (0)

    SLOAD(0, 0);
#pragma unroll 1
    for (int ks = 0; ks < 32; ks += 2) {
        SLOAD(1, ks + 1);
        SMFMA(0);
        if (ks + 2 < 32) SLOAD(0, ks + 2);
        SMFMA(1);
    }
#undef SLOAD
#undef SMFMA

#pragma unroll
    for (int ti = 0; ti < 2; ti++)
#pragma unroll
        for (int tj = 0; tj < 2; tj++)
#pragma unroll
            for (int r = 0; r < 4; r++) {
                int g = r0 + ti * 16 + ((l >> 4) << 2) + r;   // D: row=(lane>>4)*4+reg
                int c = c0 + tj * 16 + lr;                    //    col=lane&15
                hid[(size_t)g * 128 + c] = tanhf(acc[ti][tj][r] + bias[tj]);
            }
}

// ---------------- fused logits + softmax + cumsum -> coefficients, one wave per batch ----------------
__global__ __launch_bounds__(64) void k_coef(const float* __restrict__ hid,
                                             const float* __restrict__ W2,
                                             const float* __restrict__ b2,
                                             float* __restrict__ coef, int N) {
    int b = blockIdx.x, j = threadIdx.x;
    float x = -1e30f;
    if (j < N) {
        const float4* hrow = (const float4*)(hid + ((size_t)b * N + j) * 128);
        const float4* w2v = (const float4*)W2;
        float acc = 0.f;
#pragma unroll
        for (int k = 0; k < 32; k++) {
            float4 hv = hrow[k];
            float4 wv = w2v[k];
            acc += hv.x * wv.x + hv.y * wv.y + hv.z * wv.z + hv.w * wv.w;
        }
        x = acc + b2[0];
    }
    float mx = x;
#pragma unroll
    for (int o = 32; o >= 1; o >>= 1) mx = fmaxf(mx, __shfl_xor(mx, o));
    float p = (j < N) ? expf(x - mx) : 0.f;
    float tot = p;
#pragma unroll
    for (int o = 32; o >= 1; o >>= 1) tot += __shfl_xor(tot, o);
    float cs = p;
#pragma unroll
    for (int o = 1; o < 64; o <<= 1) {
        float t = __shfl_up(cs, o);
        if (j >= o) cs += t;
    }
    float inv = 1.f / tot;
    float prob = p * inv;
    float csn = cs * inv;
    float cslast = __shfl(csn, N - 1);
    if (j < N) {
        int g = b * N + j;
        coef[g * 3 + 0] = cslast - csn;   // copy_left
        coef[g * 3 + 1] = csn - prob;     // copy_right
        coef[g * 3 + 2] = prob;           // select
    }
}

// ---------------- fused gates GEMM (MFMA bf16x2) + treeLSTM + combine -> next states ----------------
// grid (8, M/64): the 8 col-tile blocks sharing A rows are consecutive -> A read once from HBM.
// Reg-double-buffered fragment loads hide L2 latency under MFMAs.
__global__ __launch_bounds__(256) void k_compose(const ushort* __restrict__ sh,
                                                 const ushort* __restrict__ sl,
                                                 const ushort* __restrict__ wth,
                                                 const ushort* __restrict__ wtl,
                                                 const float* __restrict__ cbias,
                                                 const float* __restrict__ coef,
                                                 ushort* __restrict__ dh,
                                                 ushort* __restrict__ dl,
                                                 float* __restrict__ root,
                                                 int N, int M, int cdiv) {
    int tid = threadIdx.x, l = tid & 63, wid = tid >> 6;
    int wm = wid >> 1, wn = wid & 1;
    int r0 = blockIdx.y * 64 + wm * 32;
    int cb = blockIdx.x * 32 + wn * 16;      // comp-column tile base (of 256)
    int lr = l & 15, lk = (l >> 4) << 3;

    int ab[2];
#pragma unroll
    for (int t = 0; t < 2; t++) {
        int g = r0 + t * 16 + lr;
        int q = (int)(((long long)g * cdiv) >> 20);
        ab[t] = (g + q) * 512;
    }
    int bb[5];
    float bias[5];
#pragma unroll
    for (int gt = 0; gt < 5; gt++) {
        int c = gt * 256 + cb + lr;
        bb[gt] = c * 512;
        bias[gt] = cbias[c];
    }
    f32x4 z = {0.f, 0.f, 0.f, 0.f};
    f32x4 acc[2][5] = {{z, z, z, z, z}, {z, z, z, z, z}};
    bf16x8 ah[2][2], al[2][2], bh[2][5], bl[2][5];

#define CLOAD(buf, ks) do {                                              \
        int kk_ = (ks) * 32;                                             \
        int koff_ = (kk_ < 256) ? kk_ : kk_ + 256;                       \
        _Pragma("unroll")                                                \
        for (int t = 0; t < 2; t++) {                                    \
            ah[buf][t] = *(const bf16x8*)(sh + ab[t] + koff_ + lk);      \
            al[buf][t] = *(const bf16x8*)(sl + ab[t] + koff_ + lk);      \
        }                                                                \
        _Pragma("unroll")                                                \
        for (int gt = 0; gt < 5; gt++) {                                 \
            bh[buf][gt] = *(const bf16x8*)(wth + bb[gt] + kk_ + lk);     \
            bl[buf][gt] = *(const bf16x8*)(wtl + bb[gt] + kk_ + lk);     \
        }                                                                \
    } while (0)

#define CMFMA(buf) do {                                                  \
        _Pragma("unroll")                                                \
        for (int gt = 0; gt < 5; gt++)                                   \
            _Pragma("unroll")                                            \
            for (int t = 0; t < 2; t++) {                                \
                acc[t][gt] = __builtin_amdgcn_mfma_f32_16x16x32_bf16(ah[buf][t], bh[buf][gt], acc[t][gt], 0, 0, 0); \
                acc[t][gt] = __builtin_amdgcn_mfma_f32_16x16x32_bf16(ah[buf][t], bl[buf][gt], acc[t][gt], 0, 0, 0); \
                acc[t][gt] = __builtin_amdgcn_mfma_f32_16x16x32_bf16(al[buf][t], bh[buf][gt], acc[t][gt], 0, 0, 0); \
            }                                                            \
    } while (0)

    CLOAD(0, 0);
#pragma unroll 1
    for (int ks = 0; ks < 16; ks += 2) {
        CLOAD(1, ks + 1);
        CMFMA(0);
        if (ks + 2 < 16) CLOAD(0, ks + 2);
        CMFMA(1);
    }
#undef CLOAD
#undef CMFMA

#pragma unroll
    for (int t = 0; t < 2; t++)
#pragma unroll
        for (int r = 0; r < 4; r++) {
            int m = r0 + t * 16 + ((l >> 4) << 2) + r;
            int q = (int)(((long long)m * cdiv) >> 20);
            size_t sb = (size_t)(m + q) * 512;
            int c = cb + lr;
            float cl = coef[m * 3 + 0], cr = coef[m * 3 + 1], sel = coef[m * 3 + 2];
            float h_l = bf2f(sh[sb + c])       + bf2f(sl[sb + c]);
            float c_l = bf2f(sh[sb + 256 + c]) + bf2f(sl[sb + 256 + c]);
            float h_r = bf2f(sh[sb + 512 + c]) + bf2f(sl[sb + 512 + c]);
            float c_r = bf2f(sh[sb + 768 + c]) + bf2f(sl[sb + 768 + c]);
            float gi  = acc[t][0][r] + bias[0];
            float gfl = acc[t][1][r] + bias[1];
            float gfr = acc[t][2][r] + bias[2];
            float gu  = acc[t][3][r] + bias[3];
            float go  = acc[t][4][r] + bias[4];
            float cn = sigf(gfl) * c_l + sigf(gfr) * c_r + sigf(gi) * tanhf(gu);
            float hn = sigf(go) * tanhf(cn);
            float oh = cl * h_l + cr * h_r + sel * hn;
            float oc = cl * c_l + cr * c_r + sel * cn;
            size_t ob = (size_t)m * 512 + c;
            ushort hh = bf16r(oh);
            dh[ob] = hh;
            dl[ob] = bf16r(oh - bf2f(hh));
            ushort hc = bf16r(oc);
            dh[ob + 256] = hc;
            dl[ob + 256] = bf16r(oc - bf2f(hc));
            if (N == 1) {                       // final layer: fp32 root for the MLP head
                root[ob] = oh;
                root[ob + 256] = oc;
            }
        }
}

// ---------------- generic small fp32 GEMM with optional ReLU (final MLP) ----------------
template <int ACT>
__global__ __launch_bounds__(256) void k_gemm(const float* __restrict__ A,
                                              const float* __restrict__ W,
                                              const float* __restrict__ bias,
                                              float* __restrict__ C,
                                              int M, int K, int Nc) {
    __shared__ float Xs[32][36];
    __shared__ float Ws[32][64];
    int tid = threadIdx.x;
    int r0 = blockIdx.x * 32, c0 = blockIdx.y * 64;
    int ct = tid & 15, rt = tid >> 4;
    float acc[2][4];
#pragma unroll
    for (int r = 0; r < 2; r++)
#pragma unroll
        for (int q = 0; q < 4; q++) {
            int c = c0 + ct * 4 + q;
            acc[r][q] = (c < Nc) ? bias[c] : 0.f;
        }
    for (int kk = 0; kk < K; kk += 32) {
        __syncthreads();
        {
            int m = tid >> 3, k4 = (tid & 7) << 2;
            float4 v = {0.f, 0.f, 0.f, 0.f};
            if (r0 + m < M) v = *(const float4*)(A + (size_t)(r0 + m) * K + kk + k4);
            Xs[k4 + 0][m] = v.x; Xs[k4 + 1][m] = v.y; Xs[k4 + 2][m] = v.z; Xs[k4 + 3][m] = v.w;
        }
#pragma unroll
        for (int i = 0; i < 2; i++) {
            int idx = tid + i * 256;
            int k = idx >> 4, c4 = (idx & 15) << 2;
            int c = c0 + c4;
            float4 v = {0.f, 0.f, 0.f, 0.f};
            if (c + 3 < Nc) {
                v = *(const float4*)(W + (size_t)(kk + k) * Nc + c);
            } else {
                float tmp[4] = {0.f, 0.f, 0.f, 0.f};
                for (int j = 0; j < 4; j++)
                    if (c + j < Nc) tmp[j] = W[(size_t)(kk + k) * Nc + c + j];
                v = *(float4*)tmp;
            }
            *(float4*)&Ws[k][c4] = v;
        }
        __syncthreads();
#pragma unroll
        for (int k = 0; k < 32; k++) {
            float x0 = Xs[k][rt * 2], x1 = Xs[k][rt * 2 + 1];
            float wv[4];
            *(float4*)wv = *(const float4*)&Ws[k][ct * 4];
#pragma unroll
            for (int q = 0; q < 4; q++) { acc[0][q] += x0 * wv[q]; acc[1][q] += x1 * wv[q]; }
        }
    }
#pragma unroll
    for (int r = 0; r < 2; r++) {
        int g = r0 + rt * 2 + r;
        if (g >= M) continue;
#pragma unroll
        for (int q = 0; q < 4; q++) {
            int c = c0 + ct * 4 + q;
            if (c >= Nc) continue;
            float v = acc[r][q];
            if (ACT == 1) v = fmaxf(v, 0.f);
            C[(size_t)g * Nc + c] = v;
        }
    }
}

extern "C" void kernel_launch(void* const* d_in, const int* in_sizes, int n_in,
                              void* d_out, int out_size, void* d_ws, size_t ws_size,
                              hipStream_t stream) {
    const int*   sent     = (const int*)d_in[0];
    // d_in[1] transitions: unused by reference
    const float* emb      = (const float*)d_in[2];
    const float* comp_W   = (const float*)d_in[3];
    const float* comp_b   = (const float*)d_in[4];
    const float* sel_W1   = (const float*)d_in[5];
    const float* sel_b1   = (const float*)d_in[6];
    const float* sel_W2   = (const float*)d_in[7];
    const float* sel_b2   = (const float*)d_in[8];
    const float* mlp_W0   = (const float*)d_in[9];
    const float* mlp_b0   = (const float*)d_in[10];
    const float* mlp_W1   = (const float*)d_in[11];
    const float* mlp_b1   = (const float*)d_in[12];
    const float* mlp_Wout = (const float*)d_in[13];
    const float* mlp_bout = (const float*)d_in[14];
    float* outp = (float*)d_out;

    char* p = (char*)d_ws;
    ushort* sh0  = (ushort*)p; p += (size_t)B_ * S_ * D_ * 2;
    ushort* sl0  = (ushort*)p; p += (size_t)B_ * S_ * D_ * 2;
    ushort* sh1  = (ushort*)p; p += (size_t)B_ * S_ * D_ * 2;
    ushort* sl1  = (ushort*)p; p += (size_t)B_ * S_ * D_ * 2;
    ushort* wth  = (ushort*)p; p += (size_t)1280 * 512 * 2;
    ushort* wtl  = (ushort*)p; p += (size_t)1280 * 512 * 2;
    ushort* w1th = (ushort*)p; p += (size_t)128 * 1024 * 2;
    ushort* w1tl = (ushort*)p; p += (size_t)128 * 1024 * 2;
    float*  hid  = (float*)p;  p += (size_t)B_ * 63 * SEL_ * 4;
    float*  coef = (float*)p;  p += (size_t)B_ * 63 * 3 * 4;
    float*  root = (float*)p;  p += (size_t)B_ * D_ * 4;
    float*  h1   = (float*)p;  p += (size_t)B_ * MLPD_ * 4;
    float*  h2   = (float*)p;  p += (size_t)B_ * MLPD_ * 4;

    k_embed<<<dim3(4096), dim3(256), 0, stream>>>(sent, emb, sh0, sl0);
    k_tsplit<<<dim3(20, 8), dim3(256), 0, stream>>>(comp_W, wth, wtl, 512, 1280);
    k_tsplit<<<dim3(2, 16), dim3(256), 0, stream>>>(sel_W1, w1th, w1tl, 1024, 128);

    ushort* shs = sh0; ushort* sls = sl0;
    ushort* shd = sh1; ushort* sld = sl1;
    for (int L = S_; L >= 2; --L) {
        int N = L - 1;
        int M = B_ * N;
        int cdiv = (1048576 + N - 1) / N;
        k_selhid<<<dim3(2, M / 64), dim3(256), 0, stream>>>(shs, sls, w1th, w1tl, sel_b1, hid, N, M, cdiv);
        k_coef<<<dim3(B_), dim3(64), 0, stream>>>(hid, sel_W2, sel_b2, coef, N);
        k_compose<<<dim3(8, M / 64), dim3(256), 0, stream>>>(shs, sls, wth, wtl, comp_b, coef,
                                                             shd, sld, root, N, M, cdiv);
        ushort* th = shs; shs = shd; shd = th;
        ushort* tl = sls; sls = sld; sld = tl;
    }

    k_gemm<1><<<dim3(4, 16), dim3(256), 0, stream>>>(root, mlp_W0, mlp_b0, h1, B_, 512, MLPD_);
    k_gemm<1><<<dim3(4, 16), dim3(256), 0, stream>>>(h1, mlp_W1, mlp_b1, h2, B_, 1024, MLPD_);
    k_gemm<0><<<dim3(4, 1), dim3(256), 0, stream>>>(h2, mlp_Wout, mlp_bout, outp, B_, 1024, CLS_);
}

// Round 7
// 6882.484 us; speedup vs baseline: 1.9622x; 1.0086x over previous
//
#include <hip/hip_runtime.h>
#include <hip/hip_bf16.h>
#include <math.h>

#define B_ 128
#define S_ 64
#define D_ 512
#define H_ 256
#define SEL_ 128
#define MLPD_ 1024
#define CLS_ 3

typedef __attribute__((ext_vector_type(8))) short bf16x8;
typedef __attribute__((ext_vector_type(4))) float f32x4;

__device__ __forceinline__ float sigf(float x) { return 1.f / (1.f + expf(-x)); }

// fp32 -> bf16 round-to-nearest-even (bit trick; no inf/nan in this workload)
__device__ __forceinline__ ushort bf16r(float x) {
    uint u = __float_as_uint(x);
    return (ushort)((u + 0x7fffu + ((u >> 16) & 1u)) >> 16);
}
__device__ __forceinline__ float bf2f(ushort h) { return __uint_as_float(((uint)h) << 16); }

// XCD-chunk swizzle (T1, m204 bijective): bid -> w such that XCD k = bid%8 owns a
// CONTIGUOUS chunk of w. Hardware round-robins linear bid across the 8 XCDs.
__device__ __forceinline__ int xcd_chunk(int bid, int nb) {
    int q = nb >> 3, r = nb & 7;
    int xcd = bid & 7, j = bid >> 3;
    return (xcd < r ? xcd * (q + 1) : r * (q + 1) + (xcd - r) * q) + j;
}

// ---------------- embedding gather + bf16 hi/lo split (state := hi+lo) ----------------
__global__ __launch_bounds__(256) void k_embed(const int* __restrict__ sent,
                                               const float* __restrict__ emb,
                                               ushort* __restrict__ oh,
                                               ushort* __restrict__ ol) {
    int idx = blockIdx.x * 256 + threadIdx.x;      // B*S*D/4 float4 slots
    int row = idx >> 7;
    int k4 = (idx & 127) << 2;
    int tok = sent[row];
    float4 v = *(const float4*)(emb + (size_t)tok * D_ + k4);
    ushort4 h, l;
    h.x = bf16r(v.x); l.x = bf16r(v.x - bf2f(h.x));
    h.y = bf16r(v.y); l.y = bf16r(v.y - bf2f(h.y));
    h.z = bf16r(v.z); l.z = bf16r(v.z - bf2f(h.z));
    h.w = bf16r(v.w); l.w = bf16r(v.w - bf2f(h.w));
    *(ushort4*)(oh + (size_t)row * D_ + k4) = h;
    *(ushort4*)(ol + (size_t)row * D_ + k4) = l;
}

// ---------------- transpose + split: dst[n][k] = src[k][n], K,N multiples of 64 ----------------
__global__ __launch_bounds__(256) void k_tsplit(const float* __restrict__ src,
                                                ushort* __restrict__ dh,
                                                ushort* __restrict__ dl,
                                                int K, int N) {
    __shared__ float t[64][65];
    int n0 = blockIdx.x * 64, k0 = blockIdx.y * 64;
    int tx = threadIdx.x & 63, ty = threadIdx.x >> 6;
    for (int i = ty; i < 64; i += 4)
        t[i][tx] = src[(size_t)(k0 + i) * N + n0 + tx];
    __syncthreads();
    for (int i = ty; i < 64; i += 4) {
        float v = t[tx][i];
        ushort h = bf16r(v);
        size_t o = (size_t)(n0 + i) * K + k0 + tx;
        dh[o] = h;
        dl[o] = bf16r(v - bf2f(h));
    }
}

// ---------------- selection hidden via MFMA (bf16x2 split, 3-term), reg-double-buffered ----------------
// 1D grid nb = 2*(M/64); XCD-chunk swizzle: each XCD owns a contiguous row-chunk (both col tiles).
__global__ __launch_bounds__(256) void k_selhid(const ushort* __restrict__ sh,
                                                const ushort* __restrict__ sl,
                                                const ushort* __restrict__ w1h,
                                                const ushort* __restrict__ w1l,
                                                const float* __restrict__ b1,
                                                float* __restrict__ hid,
                                                int N, int M, int cdiv) {
    int w = xcd_chunk(blockIdx.x, gridDim.x);
    int cxb = w & 1, ry = w >> 1;
    int tid = threadIdx.x, l = tid & 63, wid = tid >> 6;
    int wm = wid >> 1, wn = wid & 1;
    int r0 = ry * 64 + wm * 32;
    int c0 = cxb * 64 + wn * 32;
    int lr = l & 15, lk = (l >> 4) << 3;

    int ab[2], bb[2];
    float bias[2];
#pragma unroll
    for (int t = 0; t < 2; t++) {
        int g = r0 + t * 16 + lr;
        int q = (int)(((long long)g * cdiv) >> 20);      // g / N
        ab[t] = (g + q) * 512;
        int c = c0 + t * 16 + lr;
        bb[t] = c * 1024;
        bias[t] = b1[c];
    }
    f32x4 z = {0.f, 0.f, 0.f, 0.f};
    f32x4 acc[2][2] = {{z, z}, {z, z}};
    bf16x8 ah[2][2], al[2][2], bh[2][2], bl[2][2];

#define SLOAD(buf, ks) do {                                              \
        int kk_ = (ks) * 32;                                             \
        _Pragma("unroll")                                                \
        for (int t = 0; t < 2; t++) {                                    \
            ah[buf][t] = *(const bf16x8*)(sh + ab[t] + kk_ + lk);        \
            al[buf][t] = *(const bf16x8*)(sl + ab[t] + kk_ + lk);       \
            bh[buf][t] = *(const bf16x8*)(w1h + bb[t] + kk_ + lk);      \
            bl[buf][t] = *(const bf16x8*)(w1l + bb[t] + kk_ + lk);      \
        }                                                                \
    } while (0)

#define SMFMA(buf) do {                                                  \
        _Pragma("unroll")                                                \
        for (int ti = 0; ti < 2; ti++)                                   \
            _Pragma("unroll")                                            \
            for (int tj = 0; tj < 2; tj++) {                             \
                acc[ti][tj] = __builtin_amdgcn_mfma_f32_16x16x32_bf16(ah[buf][ti], bh[buf][tj], acc[ti][tj], 0, 0, 0); \
                acc[ti][tj] = __builtin_amdgcn_mfma_f32_16x16x32_bf16(ah[buf][ti], bl[buf][tj], acc[ti][tj], 0, 0, 0); \
                acc[ti][tj] = __builtin_amdgcn_mfma_f32_16x16x32_bf16(al[buf][ti], bh[buf][tj], acc[ti][tj], 0, 0, 0); \
            }                                                            \
    } while (0)

    SLOAD(0, 0);
#pragma unroll 1
    for (int ks = 0; ks < 32; ks += 2) {
        SLOAD(1, ks + 1);
        SMFMA(0);
        if (ks + 2 < 32) SLOAD(0, ks + 2);
        SMFMA(1);
    }
#undef SLOAD
#undef SMFMA

#pragma unroll
    for (int ti = 0; ti < 2; ti++)
#pragma unroll
        for (int tj = 0; tj < 2; tj++)
#pragma unroll
            for (int r = 0; r < 4; r++) {
                int g = r0 + ti * 16 + ((l >> 4) << 2) + r;   // D: row=(lane>>4)*4+reg
                int c = c0 + tj * 16 + lr;                    //    col=lane&15
                hid[(size_t)g * 128 + c] = tanhf(acc[ti][tj][r] + bias[tj]);
            }
}

// ---------------- fused logits + softmax + cumsum -> coefficients, one wave per batch ----------------
__global__ __launch_bounds__(64) void k_coef(const float* __restrict__ hid,
                                             const float* __restrict__ W2,
                                             const float* __restrict__ b2,
                                             float* __restrict__ coef, int N) {
    int b = blockIdx.x, j = threadIdx.x;
    float x = -1e30f;
    if (j < N) {
        const float4* hrow = (const float4*)(hid + ((size_t)b * N + j) * 128);
        const float4* w2v = (const float4*)W2;
        float acc = 0.f;
#pragma unroll
        for (int k = 0; k < 32; k++) {
            float4 hv = hrow[k];
            float4 wv = w2v[k];
            acc += hv.x * wv.x + hv.y * wv.y + hv.z * wv.z + hv.w * wv.w;
        }
        x = acc + b2[0];
    }
    float mx = x;
#pragma unroll
    for (int o = 32; o >= 1; o >>= 1) mx = fmaxf(mx, __shfl_xor(mx, o));
    float p = (j < N) ? expf(x - mx) : 0.f;
    float tot = p;
#pragma unroll
    for (int o = 32; o >= 1; o >>= 1) tot += __shfl_xor(tot, o);
    float cs = p;
#pragma unroll
    for (int o = 1; o < 64; o <<= 1) {
        float t = __shfl_up(cs, o);
        if (j >= o) cs += t;
    }
    float inv = 1.f / tot;
    float prob = p * inv;
    float csn = cs * inv;
    float cslast = __shfl(csn, N - 1);
    if (j < N) {
        int g = b * N + j;
        coef[g * 3 + 0] = cslast - csn;   // copy_left
        coef[g * 3 + 1] = csn - prob;     // copy_right
        coef[g * 3 + 2] = prob;           // select
    }
}

// ---------------- fused gates GEMM (MFMA bf16x2) + treeLSTM + combine -> next states ----------------
// 1D grid nb = 8*(M/64); XCD-chunk swizzle: each XCD owns a contiguous row-chunk with ALL 8
// col-tiles -> per-XCD L2 working set = A-chunk (~2MB) + full B (2.6MB). Consecutive layers
// map the same rows to the same XCD, so prior write-back is read from local L2.
__global__ __launch_bounds__(256) void k_compose(const ushort* __restrict__ sh,
                                                 const ushort* __restrict__ sl,
                                                 const ushort* __restrict__ wth,
                                                 const ushort* __restrict__ wtl,
                                                 const float* __restrict__ cbias,
                                                 const float* __restrict__ coef,
                                                 ushort* __restrict__ dh,
                                                 ushort* __restrict__ dl,
                                                 float* __restrict__ root,
                                                 int N, int M, int cdiv) {
    int w = xcd_chunk(blockIdx.x, gridDim.x);
    int cx = w & 7, ry = w >> 3;
    int tid = threadIdx.x, l = tid & 63, wid = tid >> 6;
    int wm = wid >> 1, wn = wid & 1;
    int r0 = ry * 64 + wm * 32;
    int cb = cx * 32 + wn * 16;      // comp-column tile base (of 256)
    int lr = l & 15, lk = (l >> 4) << 3;

    int ab[2];
#pragma unroll
    for (int t = 0; t < 2; t++) {
        int g = r0 + t * 16 + lr;
        int q = (int)(((long long)g * cdiv) >> 20);
        ab[t] = (g + q) * 512;
    }
    int bb[5];
    float bias[5];
#pragma unroll
    for (int gt = 0; gt < 5; gt++) {
        int c = gt * 256 + cb + lr;
        bb[gt] = c * 512;
        bias[gt] = cbias[c];
    }
    f32x4 z = {0.f, 0.f, 0.f, 0.f};
    f32x4 acc[2][5] = {{z, z, z, z, z}, {z, z, z, z, z}};
    bf16x8 ah[2][2], al[2][2], bh[2][5], bl[2][5];

#define CLOAD(buf, ks) do {                                              \
        int kk_ = (ks) * 32;                                             \
        int koff_ = (kk_ < 256) ? kk_ : kk_ + 256;                       \
        _Pragma("unroll")                                                \
        for (int t = 0; t < 2; t++) {                                    \
            ah[buf][t] = *(const bf16x8*)(sh + ab[t] + koff_ + lk);      \
            al[buf][t] = *(const bf16x8*)(sl + ab[t] + koff_ + lk);      \
        }                                                                \
        _Pragma("unroll")                                                \
        for (int gt = 0; gt < 5; gt++) {                                 \
            bh[buf][gt] = *(const bf16x8*)(wth + bb[gt] + kk_ + lk);     \
            bl[buf][gt] = *(const bf16x8*)(wtl + bb[gt] + kk_ + lk);     \
        }                                                                \
    } while (0)

#define CMFMA(buf) do {                                                  \
        _Pragma("unroll")                                                \
        for (int gt = 0; gt < 5; gt++)                                   \
            _Pragma("unroll")                                            \
            for (int t = 0; t < 2; t++) {                                \
                acc[t][gt] = __builtin_amdgcn_mfma_f32_16x16x32_bf16(ah[buf][t], bh[buf][gt], acc[t][gt], 0, 0, 0); \
                acc[t][gt] = __builtin_amdgcn_mfma_f32_16x16x32_bf16(ah[buf][t], bl[buf][gt], acc[t][gt], 0, 0, 0); \
                acc[t][gt] = __builtin_amdgcn_mfma_f32_16x16x32_bf16(al[buf][t], bh[buf][gt], acc[t][gt], 0, 0, 0); \
            }                                                            \
    } while (0)

    CLOAD(0, 0);
#pragma unroll 1
    for (int ks = 0; ks < 16; ks += 2) {
        CLOAD(1, ks + 1);
        CMFMA(0);
        if (ks + 2 < 16) CLOAD(0, ks + 2);
        CMFMA(1);
    }
#undef CLOAD
#undef CMFMA

#pragma unroll
    for (int t = 0; t < 2; t++)
#pragma unroll
        for (int r = 0; r < 4; r++) {
            int m = r0 + t * 16 + ((l >> 4) << 2) + r;
            int q = (int)(((long long)m * cdiv) >> 20);
            size_t sb = (size_t)(m + q) * 512;
            int c = cb + lr;
            float cl = coef[m * 3 + 0], cr = coef[m * 3 + 1], sel = coef[m * 3 + 2];
            float h_l = bf2f(sh[sb + c])       + bf2f(sl[sb + c]);
            float c_l = bf2f(sh[sb + 256 + c]) + bf2f(sl[sb + 256 + c]);
            float h_r = bf2f(sh[sb + 512 + c]) + bf2f(sl[sb + 512 + c]);
            float c_r = bf2f(sh[sb + 768 + c]) + bf2f(sl[sb + 768 + c]);
            float gi  = acc[t][0][r] + bias[0];
            float gfl = acc[t][1][r] + bias[1];
            float gfr = acc[t][2][r] + bias[2];
            float gu  = acc[t][3][r] + bias[3];
            float go  = acc[t][4][r] + bias[4];
            float cn = sigf(gfl) * c_l + sigf(gfr) * c_r + sigf(gi) * tanhf(gu);
            float hn = sigf(go) * tanhf(cn);
            float oh = cl * h_l + cr * h_r + sel * hn;
            float oc = cl * c_l + cr * c_r + sel * cn;
            size_t ob = (size_t)m * 512 + c;
            ushort hh = bf16r(oh);
            dh[ob] = hh;
            dl[ob] = bf16r(oh - bf2f(hh));
            ushort hc = bf16r(oc);
            dh[ob + 256] = hc;
            dl[ob + 256] = bf16r(oc - bf2f(hc));
            if (N == 1) {                       // final layer: fp32 root for the MLP head
                root[ob] = oh;
                root[ob + 256] = oc;
            }
        }
}

// ---------------- generic small fp32 GEMM with optional ReLU (final MLP) ----------------
template <int ACT>
__global__ __launch_bounds__(256) void k_gemm(const float* __restrict__ A,
                                              const float* __restrict__ W,
                                              const float* __restrict__ bias,
                                              float* __restrict__ C,
                                              int M, int K, int Nc) {
    __shared__ float Xs[32][36];
    __shared__ float Ws[32][64];
    int tid = threadIdx.x;
    int r0 = blockIdx.x * 32, c0 = blockIdx.y * 64;
    int ct = tid & 15, rt = tid >> 4;
    float acc[2][4];
#pragma unroll
    for (int r = 0; r < 2; r++)
#pragma unroll
        for (int q = 0; q < 4; q++) {
            int c = c0 + ct * 4 + q;
            acc[r][q] = (c < Nc) ? bias[c] : 0.f;
        }
    for (int kk = 0; kk < K; kk += 32) {
        __syncthreads();
        {
            int m = tid >> 3, k4 = (tid & 7) << 2;
            float4 v = {0.f, 0.f, 0.f, 0.f};
            if (r0 + m < M) v = *(const float4*)(A + (size_t)(r0 + m) * K + kk + k4);
            Xs[k4 + 0][m] = v.x; Xs[k4 + 1][m] = v.y; Xs[k4 + 2][m] = v.z; Xs[k4 + 3][m] = v.w;
        }
#pragma unroll
        for (int i = 0; i < 2; i++) {
            int idx = tid + i * 256;
            int k = idx >> 4, c4 = (idx & 15) << 2;
            int c = c0 + c4;
            float4 v = {0.f, 0.f, 0.f, 0.f};
            if (c + 3 < Nc) {
                v = *(const float4*)(W + (size_t)(kk + k) * Nc + c);
            } else {
                float tmp[4] = {0.f, 0.f, 0.f, 0.f};
                for (int j = 0; j < 4; j++)
                    if (c + j < Nc) tmp[j] = W[(size_t)(kk + k) * Nc + c + j];
                v = *(float4*)tmp;
            }
            *(float4*)&Ws[k][c4] = v;
        }
        __syncthreads();
#pragma unroll
        for (int k = 0; k < 32; k++) {
            float x0 = Xs[k][rt * 2], x1 = Xs[k][rt * 2 + 1];
            float wv[4];
            *(float4*)wv = *(const float4*)&Ws[k][ct * 4];
#pragma unroll
            for (int q = 0; q < 4; q++) { acc[0][q] += x0 * wv[q]; acc[1][q] += x1 * wv[q]; }
        }
    }
#pragma unroll
    for (int r = 0; r < 2; r++) {
        int g = r0 + rt * 2 + r;
        if (g >= M) continue;
#pragma unroll
        for (int q = 0; q < 4; q++) {
            int c = c0 + ct * 4 + q;
            if (c >= Nc) continue;
            float v = acc[r][q];
            if (ACT == 1) v = fmaxf(v, 0.f);
            C[(size_t)g * Nc + c] = v;
        }
    }
}

extern "C" void kernel_launch(void* const* d_in, const int* in_sizes, int n_in,
                              void* d_out, int out_size, void* d_ws, size_t ws_size,
                              hipStream_t stream) {
    const int*   sent     = (const int*)d_in[0];
    // d_in[1] transitions: unused by reference
    const float* emb      = (const float*)d_in[2];
    const float* comp_W   = (const float*)d_in[3];
    const float* comp_b   = (const float*)d_in[4];
    const float* sel_W1   = (const float*)d_in[5];
    const float* sel_b1   = (const float*)d_in[6];
    const float* sel_W2   = (const float*)d_in[7];
    const float* sel_b2   = (const float*)d_in[8];
    const float* mlp_W0   = (const float*)d_in[9];
    const float* mlp_b0   = (const float*)d_in[10];
    const float* mlp_W1   = (const float*)d_in[11];
    const float* mlp_b1   = (const float*)d_in[12];
    const float* mlp_Wout = (const float*)d_in[13];
    const float* mlp_bout = (const float*)d_in[14];
    float* outp = (float*)d_out;

    char* p = (char*)d_ws;
    ushort* sh0  = (ushort*)p; p += (size_t)B_ * S_ * D_ * 2;
    ushort* sl0  = (ushort*)p; p += (size_t)B_ * S_ * D_ * 2;
    ushort* sh1  = (ushort*)p; p += (size_t)B_ * S_ * D_ * 2;
    ushort* sl1  = (ushort*)p; p += (size_t)B_ * S_ * D_ * 2;
    ushort* wth  = (ushort*)p; p += (size_t)1280 * 512 * 2;
    ushort* wtl  = (ushort*)p; p += (size_t)1280 * 512 * 2;
    ushort* w1th = (ushort*)p; p += (size_t)128 * 1024 * 2;
    ushort* w1tl = (ushort*)p; p += (size_t)128 * 1024 * 2;
    float*  hid  = (float*)p;  p += (size_t)B_ * 63 * SEL_ * 4;
    float*  coef = (float*)p;  p += (size_t)B_ * 63 * 3 * 4;
    float*  root = (float*)p;  p += (size_t)B_ * D_ * 4;
    float*  h1   = (float*)p;  p += (size_t)B_ * MLPD_ * 4;
    float*  h2   = (float*)p;  p += (size_t)B_ * MLPD_ * 4;

    k_embed<<<dim3(4096), dim3(256), 0, stream>>>(sent, emb, sh0, sl0);
    k_tsplit<<<dim3(20, 8), dim3(256), 0, stream>>>(comp_W, wth, wtl, 512, 1280);
    k_tsplit<<<dim3(2, 16), dim3(256), 0, stream>>>(sel_W1, w1th, w1tl, 1024, 128);

    ushort* shs = sh0; ushort* sls = sl0;
    ushort* shd = sh1; ushort* sld = sl1;
    for (int L = S_; L >= 2; --L) {
        int N = L - 1;
        int M = B_ * N;
        int cdiv = (1048576 + N - 1) / N;
        k_selhid<<<dim3(2 * (M / 64)), dim3(256), 0, stream>>>(shs, sls, w1th, w1tl, sel_b1, hid, N, M, cdiv);
        k_coef<<<dim3(B_), dim3(64), 0, stream>>>(hid, sel_W2, sel_b2, coef, N);
        k_compose<<<dim3(8 * (M / 64)), dim3(256), 0, stream>>>(shs, sls, wth, wtl, comp_b, coef,
                                                                shd, sld, root, N, M, cdiv);
        ushort* th = shs; shs = shd; shd = th;
        ushort* tl = sls; sls = sld; sld = tl;
    }

    k_gemm<1><<<dim3(4, 16), dim3(256), 0, stream>>>(root, mlp_W0, mlp_b0, h1, B_, 512, MLPD_);
    k_gemm<1><<<dim3(4, 16), dim3(256), 0, stream>>>(h1, mlp_W1, mlp_b1, h2, B_, 1024, MLPD_);
    k_gemm<0><<<dim3(4, 1), dim3(256), 0, stream>>>(h2, mlp_Wout, mlp_bout, outp, B_, 1024, CLS_);
}

// Round 8
// 3877.952 us; speedup vs baseline: 3.4825x; 1.7748x over previous
//
#include <hip/hip_runtime.h>
#include <hip/hip_bf16.h>
#include <math.h>

#define B_ 128
#define S_ 64
#define D_ 512
#define H_ 256
#define SEL_ 128
#define MLPD_ 1024
#define CLS_ 3

typedef __attribute__((ext_vector_type(8))) short bf16x8;
typedef __attribute__((ext_vector_type(4))) float f32x4;

__device__ __forceinline__ float sigf(float x) { return 1.f / (1.f + expf(-x)); }

// fp32 -> bf16 round-to-nearest-even (bit trick; no inf/nan in this workload)
__device__ __forceinline__ ushort bf16r(float x) {
    uint u = __float_as_uint(x);
    return (ushort)((u + 0x7fffu + ((u >> 16) & 1u)) >> 16);
}
__device__ __forceinline__ float bf2f(ushort h) { return __uint_as_float(((uint)h) << 16); }

// XCD-chunk swizzle (T1, m204 bijective): XCD k = bid%8 owns a contiguous chunk of w.
__device__ __forceinline__ int xcd_chunk(int bid, int nb) {
    int q = nb >> 3, r = nb & 7;
    int xcd = bid & 7, j = bid >> 3;
    return (xcd < r ? xcd * (q + 1) : r * (q + 1) + (xcd - r) * q) + j;
}

// ---------------- embedding gather + bf16 hi/lo split (state := hi+lo) ----------------
__global__ __launch_bounds__(256) void k_embed(const int* __restrict__ sent,
                                               const float* __restrict__ emb,
                                               ushort* __restrict__ oh,
                                               ushort* __restrict__ ol) {
    int idx = blockIdx.x * 256 + threadIdx.x;      // B*S*D/4 float4 slots
    int row = idx >> 7;
    int k4 = (idx & 127) << 2;
    int tok = sent[row];
    float4 v = *(const float4*)(emb + (size_t)tok * D_ + k4);
    ushort4 h, l;
    h.x = bf16r(v.x); l.x = bf16r(v.x - bf2f(h.x));
    h.y = bf16r(v.y); l.y = bf16r(v.y - bf2f(h.y));
    h.z = bf16r(v.z); l.z = bf16r(v.z - bf2f(h.z));
    h.w = bf16r(v.w); l.w = bf16r(v.w - bf2f(h.w));
    *(ushort4*)(oh + (size_t)row * D_ + k4) = h;
    *(ushort4*)(ol + (size_t)row * D_ + k4) = l;
}

// ---------------- transpose + split: dst[n][k] = src[k][n], K,N multiples of 64 ----------------
__global__ __launch_bounds__(256) void k_tsplit(const float* __restrict__ src,
                                                ushort* __restrict__ dh,
                                                ushort* __restrict__ dl,
                                                int K, int N) {
    __shared__ float t[64][65];
    int n0 = blockIdx.x * 64, k0 = blockIdx.y * 64;
    int tx = threadIdx.x & 63, ty = threadIdx.x >> 6;
    for (int i = ty; i < 64; i += 4)
        t[i][tx] = src[(size_t)(k0 + i) * N + n0 + tx];
    __syncthreads();
    for (int i = ty; i < 64; i += 4) {
        float v = t[tx][i];
        ushort h = bf16r(v);
        size_t o = (size_t)(n0 + i) * K + k0 + tx;
        dh[o] = h;
        dl[o] = bf16r(v - bf2f(h));
    }
}

// ---------------- selection hidden: LDS-staged MFMA GEMM (bf16x2, 3-term) ----------------
// Block tile 64 rows x 64 cols, K=1024, BK=32. Padded LDS rows (40 bf16) -> ~2-way banks.
__global__ __launch_bounds__(256) void k_selhid(const ushort* __restrict__ sh,
                                                const ushort* __restrict__ sl,
                                                const ushort* __restrict__ w1h,
                                                const ushort* __restrict__ w1l,
                                                const float* __restrict__ b1,
                                                float* __restrict__ hid,
                                                int N, int M, int cdiv) {
    __shared__ __align__(16) ushort sAm[2][64][40];
    __shared__ __align__(16) ushort sBm[2][64][40];
    __shared__ int rb[64];
    int w = xcd_chunk(blockIdx.x, gridDim.x);
    int cxb = w & 1, ry = w >> 1;
    int tid = threadIdx.x, l = tid & 63, wid = tid >> 6;
    int wm = wid >> 1, wn = wid & 1;
    int r0 = ry * 64;
    int c0b = cxb * 64;
    int lr = l & 15, lk = (l >> 4) << 3;

    if (tid < 64) {
        int g = r0 + tid;
        int q = (int)(((long long)g * cdiv) >> 20);      // g / N
        rb[tid] = (g + q) * 512;
    }
    __syncthreads();

    float bias[2];
#pragma unroll
    for (int t = 0; t < 2; t++) bias[t] = b1[c0b + wn * 32 + t * 16 + lr];

    const ushort* aSrc[2]; ushort* aDst[2];
    const ushort* bSrc[2]; ushort* bDst[2];
#pragma unroll
    for (int i = 0; i < 2; i++) {
        int idx = tid + i * 256;
        int p = idx >> 8, rem = idx & 255;
        int r = rem >> 2, s = rem & 3;
        aSrc[i] = (p ? sl : sh) + rb[r] + s * 8;
        aDst[i] = &sAm[p][r][s * 8];
        bSrc[i] = (p ? w1l : w1h) + (c0b + r) * 1024 + s * 8;
        bDst[i] = &sBm[p][r][s * 8];
    }

    f32x4 z = {0.f, 0.f, 0.f, 0.f};
    f32x4 acc[2][2] = {{z, z}, {z, z}};
    bf16x8 gA[2], gB[2];

#define SSTAGE_LOAD(kk) do {                                               \
        _Pragma("unroll")                                                  \
        for (int i = 0; i < 2; i++) {                                      \
            gA[i] = *(const bf16x8*)(aSrc[i] + (kk));                      \
            gB[i] = *(const bf16x8*)(bSrc[i] + (kk));                      \
        }                                                                  \
    } while (0)
#define SSTAGE_WRITE() do {                                                \
        _Pragma("unroll")                                                  \
        for (int i = 0; i < 2; i++) {                                      \
            *(bf16x8*)aDst[i] = gA[i];                                     \
            *(bf16x8*)bDst[i] = gB[i];                                     \
        }                                                                  \
    } while (0)

    SSTAGE_LOAD(0);
    SSTAGE_WRITE();
    __syncthreads();

    for (int ks = 0; ks < 32; ks++) {
        if (ks < 31) SSTAGE_LOAD((ks + 1) * 32);
        bf16x8 fa[2][2], fb[2][2];
#pragma unroll
        for (int t = 0; t < 2; t++) {
            int ar = wm * 32 + t * 16 + lr;
            fa[0][t] = *(const bf16x8*)&sAm[0][ar][lk];
            fa[1][t] = *(const bf16x8*)&sAm[1][ar][lk];
            int bc = wn * 32 + t * 16 + lr;
            fb[0][t] = *(const bf16x8*)&sBm[0][bc][lk];
            fb[1][t] = *(const bf16x8*)&sBm[1][bc][lk];
        }
#pragma unroll
        for (int ti = 0; ti < 2; ti++)
#pragma unroll
            for (int tj = 0; tj < 2; tj++) {
                acc[ti][tj] = __builtin_amdgcn_mfma_f32_16x16x32_bf16(fa[0][ti], fb[0][tj], acc[ti][tj], 0, 0, 0);
                acc[ti][tj] = __builtin_amdgcn_mfma_f32_16x16x32_bf16(fa[0][ti], fb[1][tj], acc[ti][tj], 0, 0, 0);
                acc[ti][tj] = __builtin_amdgcn_mfma_f32_16x16x32_bf16(fa[1][ti], fb[0][tj], acc[ti][tj], 0, 0, 0);
            }
        __syncthreads();
        if (ks < 31) {
            SSTAGE_WRITE();
            __syncthreads();
        }
    }
#undef SSTAGE_LOAD
#undef SSTAGE_WRITE

#pragma unroll
    for (int ti = 0; ti < 2; ti++)
#pragma unroll
        for (int tj = 0; tj < 2; tj++)
#pragma unroll
            for (int r = 0; r < 4; r++) {
                int g = r0 + wm * 32 + ti * 16 + ((l >> 4) << 2) + r;   // D: row=(lane>>4)*4+reg
                int c = c0b + wn * 32 + tj * 16 + lr;                   //    col=lane&15
                hid[(size_t)g * 128 + c] = tanhf(acc[ti][tj][r] + bias[tj]);
            }
}

// ---------------- fused logits + softmax + cumsum -> coefficients, one wave per batch ----------------
__global__ __launch_bounds__(64) void k_coef(const float* __restrict__ hid,
                                             const float* __restrict__ W2,
                                             const float* __restrict__ b2,
                                             float* __restrict__ coef, int N) {
    int b = blockIdx.x, j = threadIdx.x;
    float x = -1e30f;
    if (j < N) {
        const float4* hrow = (const float4*)(hid + ((size_t)b * N + j) * 128);
        const float4* w2v = (const float4*)W2;
        float acc = 0.f;
#pragma unroll
        for (int k = 0; k < 32; k++) {
            float4 hv = hrow[k];
            float4 wv = w2v[k];
            acc += hv.x * wv.x + hv.y * wv.y + hv.z * wv.z + hv.w * wv.w;
        }
        x = acc + b2[0];
    }
    float mx = x;
#pragma unroll
    for (int o = 32; o >= 1; o >>= 1) mx = fmaxf(mx, __shfl_xor(mx, o));
    float p = (j < N) ? expf(x - mx) : 0.f;
    float tot = p;
#pragma unroll
    for (int o = 32; o >= 1; o >>= 1) tot += __shfl_xor(tot, o);
    float cs = p;
#pragma unroll
    for (int o = 1; o < 64; o <<= 1) {
        float t = __shfl_up(cs, o);
        if (j >= o) cs += t;
    }
    float inv = 1.f / tot;
    float prob = p * inv;
    float csn = cs * inv;
    float cslast = __shfl(csn, N - 1);
    if (j < N) {
        int g = b * N + j;
        coef[g * 3 + 0] = cslast - csn;   // copy_left
        coef[g * 3 + 1] = csn - prob;     // copy_right
        coef[g * 3 + 2] = prob;           // select
    }
}

// ---------------- fused gates GEMM: LDS-staged MFMA (bf16x2) + treeLSTM + combine ----------------
// Block tile 64 rows x 32 comp-cols (160 actual cols over 5 gate strips), K=512, BK=32.
// Single LDS buffer, 2 barriers/step; loads for k+1 issued before MFMA k (T14 split).
__global__ __launch_bounds__(256) void k_compose(const ushort* __restrict__ sh,
                                                 const ushort* __restrict__ sl,
                                                 const ushort* __restrict__ wth,
                                                 const ushort* __restrict__ wtl,
                                                 const float* __restrict__ cbias,
                                                 const float* __restrict__ coef,
                                                 ushort* __restrict__ dh,
                                                 ushort* __restrict__ dl,
                                                 float* __restrict__ root,
                                                 int N, int M, int cdiv) {
    __shared__ __align__(16) ushort sAm[2][64][40];
    __shared__ __align__(16) ushort sBm[2][160][40];
    __shared__ int rb[64];
    int w = xcd_chunk(blockIdx.x, gridDim.x);
    int cx = w & 7, ry = w >> 3;
    int tid = threadIdx.x, l = tid & 63, wid = tid >> 6;
    int wm = wid >> 1, wn = wid & 1;
    int r0 = ry * 64;
    int cb_blk = cx * 32;
    int cbw = cb_blk + wn * 16;
    int lr = l & 15, lk = (l >> 4) << 3;

    if (tid < 64) {
        int g = r0 + tid;
        int q = (int)(((long long)g * cdiv) >> 20);
        rb[tid] = (g + q) * 512;
    }
    __syncthreads();

    float bias[5];
#pragma unroll
    for (int gt = 0; gt < 5; gt++) bias[gt] = cbias[gt * 256 + cbw + lr];

    const ushort* aSrc[2]; ushort* aDst[2];
#pragma unroll
    for (int i = 0; i < 2; i++) {
        int idx = tid + i * 256;
        int p = idx >> 8, rem = idx & 255;
        int r = rem >> 2, s = rem & 3;
        aSrc[i] = (p ? sl : sh) + rb[r] + s * 8;
        aDst[i] = &sAm[p][r][s * 8];
    }
    const ushort* bSrc[5]; ushort* bDst[5];
#pragma unroll
    for (int j = 0; j < 5; j++) {
        int idx = tid + j * 256;
        int p = (idx >= 640) ? 1 : 0;
        int rem = idx - p * 640;
        int br = rem >> 2, s = rem & 3;
        int col = (br >> 5) * 256 + cb_blk + (br & 31);
        bSrc[j] = (p ? wtl : wth) + col * 512 + s * 8;
        bDst[j] = &sBm[p][br][s * 8];
    }

    f32x4 z = {0.f, 0.f, 0.f, 0.f};
    f32x4 acc[2][5] = {{z, z, z, z, z}, {z, z, z, z, z}};
    bf16x8 gA[2], gB[5];

#define CSTAGE_LOAD(kk) do {                                               \
        int koff_ = ((kk) < 256) ? (kk) : (kk) + 256;                      \
        _Pragma("unroll")                                                  \
        for (int i = 0; i < 2; i++) gA[i] = *(const bf16x8*)(aSrc[i] + koff_); \
        _Pragma("unroll")                                                  \
        for (int j = 0; j < 5; j++) gB[j] = *(const bf16x8*)(bSrc[j] + (kk)); \
    } while (0)
#define CSTAGE_WRITE() do {                                                \
        _Pragma("unroll")                                                  \
        for (int i = 0; i < 2; i++) *(bf16x8*)aDst[i] = gA[i];             \
        _Pragma("unroll")                                                  \
        for (int j = 0; j < 5; j++) *(bf16x8*)bDst[j] = gB[j];             \
    } while (0)

    CSTAGE_LOAD(0);
    CSTAGE_WRITE();
    __syncthreads();

    for (int ks = 0; ks < 16; ks++) {
        if (ks < 15) CSTAGE_LOAD((ks + 1) * 32);
        bf16x8 fa[2][2], fb[2][5];
#pragma unroll
        for (int t = 0; t < 2; t++) {
            int ar = wm * 32 + t * 16 + lr;
            fa[0][t] = *(const bf16x8*)&sAm[0][ar][lk];
            fa[1][t] = *(const bf16x8*)&sAm[1][ar][lk];
        }
#pragma unroll
        for (int gt = 0; gt < 5; gt++) {
            int br = gt * 32 + wn * 16 + lr;
            fb[0][gt] = *(const bf16x8*)&sBm[0][br][lk];
            fb[1][gt] = *(const bf16x8*)&sBm[1][br][lk];
        }
#pragma unroll
        for (int gt = 0; gt < 5; gt++)
#pragma unroll
            for (int t = 0; t < 2; t++) {
                acc[t][gt] = __builtin_amdgcn_mfma_f32_16x16x32_bf16(fa[0][t], fb[0][gt], acc[t][gt], 0, 0, 0);
                acc[t][gt] = __builtin_amdgcn_mfma_f32_16x16x32_bf16(fa[0][t], fb[1][gt], acc[t][gt], 0, 0, 0);
                acc[t][gt] = __builtin_amdgcn_mfma_f32_16x16x32_bf16(fa[1][t], fb[0][gt], acc[t][gt], 0, 0, 0);
            }
        __syncthreads();
        if (ks < 15) {
            CSTAGE_WRITE();
            __syncthreads();
        }
    }
#undef CSTAGE_LOAD
#undef CSTAGE_WRITE

#pragma unroll
    for (int t = 0; t < 2; t++)
#pragma unroll
        for (int r = 0; r < 4; r++) {
            int lrow = wm * 32 + t * 16 + ((l >> 4) << 2) + r;
            int m = r0 + lrow;
            size_t sb = (size_t)rb[lrow];
            int c = cbw + lr;
            float cl = coef[m * 3 + 0], cr = coef[m * 3 + 1], sel = coef[m * 3 + 2];
            float h_l = bf2f(sh[sb + c])       + bf2f(sl[sb + c]);
            float c_l = bf2f(sh[sb + 256 + c]) + bf2f(sl[sb + 256 + c]);
            float h_r = bf2f(sh[sb + 512 + c]) + bf2f(sl[sb + 512 + c]);
            float c_r = bf2f(sh[sb + 768 + c]) + bf2f(sl[sb + 768 + c]);
            float gi  = acc[t][0][r] + bias[0];
            float gfl = acc[t][1][r] + bias[1];
            float gfr = acc[t][2][r] + bias[2];
            float gu  = acc[t][3][r] + bias[3];
            float go  = acc[t][4][r] + bias[4];
            float cn = sigf(gfl) * c_l + sigf(gfr) * c_r + sigf(gi) * tanhf(gu);
            float hn = sigf(go) * tanhf(cn);
            float oh = cl * h_l + cr * h_r + sel * hn;
            float oc = cl * c_l + cr * c_r + sel * cn;
            size_t ob = (size_t)m * 512 + c;
            ushort hh = bf16r(oh);
            dh[ob] = hh;
            dl[ob] = bf16r(oh - bf2f(hh));
            ushort hc = bf16r(oc);
            dh[ob + 256] = hc;
            dl[ob + 256] = bf16r(oc - bf2f(hc));
            if (N == 1) {                       // final layer: fp32 root for the MLP head
                root[ob] = oh;
                root[ob + 256] = oc;
            }
        }
}

// ---------------- generic small fp32 GEMM with optional ReLU (final MLP) ----------------
template <int ACT>
__global__ __launch_bounds__(256) void k_gemm(const float* __restrict__ A,
                                              const float* __restrict__ W,
                                              const float* __restrict__ bias,
                                              float* __restrict__ C,
                                              int M, int K, int Nc) {
    __shared__ float Xs[32][36];
    __shared__ float Ws[32][64];
    int tid = threadIdx.x;
    int r0 = blockIdx.x * 32, c0 = blockIdx.y * 64;
    int ct = tid & 15, rt = tid >> 4;
    float acc[2][4];
#pragma unroll
    for (int r = 0; r < 2; r++)
#pragma unroll
        for (int q = 0; q < 4; q++) {
            int c = c0 + ct * 4 + q;
            acc[r][q] = (c < Nc) ? bias[c] : 0.f;
        }
    for (int kk = 0; kk < K; kk += 32) {
        __syncthreads();
        {
            int m = tid >> 3, k4 = (tid & 7) << 2;
            float4 v = {0.f, 0.f, 0.f, 0.f};
            if (r0 + m < M) v = *(const float4*)(A + (size_t)(r0 + m) * K + kk + k4);
            Xs[k4 + 0][m] = v.x; Xs[k4 + 1][m] = v.y; Xs[k4 + 2][m] = v.z; Xs[k4 + 3][m] = v.w;
        }
#pragma unroll
        for (int i = 0; i < 2; i++) {
            int idx = tid + i * 256;
            int k = idx >> 4, c4 = (idx & 15) << 2;
            int c = c0 + c4;
            float4 v = {0.f, 0.f, 0.f, 0.f};
            if (c + 3 < Nc) {
                v = *(const float4*)(W + (size_t)(kk + k) * Nc + c);
            } else {
                float tmp[4] = {0.f, 0.f, 0.f, 0.f};
                for (int j = 0; j < 4; j++)
                    if (c + j < Nc) tmp[j] = W[(size_t)(kk + k) * Nc + c + j];
                v = *(float4*)tmp;
            }
            *(float4*)&Ws[k][c4] = v;
        }
        __syncthreads();
#pragma unroll
        for (int k = 0; k < 32; k++) {
            float x0 = Xs[k][rt * 2], x1 = Xs[k][rt * 2 + 1];
            float wv[4];
            *(float4*)wv = *(const float4*)&Ws[k][ct * 4];
#pragma unroll
            for (int q = 0; q < 4; q++) { acc[0][q] += x0 * wv[q]; acc[1][q] += x1 * wv[q]; }
        }
    }
#pragma unroll
    for (int r = 0; r < 2; r++) {
        int g = r0 + rt * 2 + r;
        if (g >= M) continue;
#pragma unroll
        for (int q = 0; q < 4; q++) {
            int c = c0 + ct * 4 + q;
            if (c >= Nc) continue;
            float v = acc[r][q];
            if (ACT == 1) v = fmaxf(v, 0.f);
            C[(size_t)g * Nc + c] = v;
        }
    }
}

extern "C" void kernel_launch(void* const* d_in, const int* in_sizes, int n_in,
                              void* d_out, int out_size, void* d_ws, size_t ws_size,
                              hipStream_t stream) {
    const int*   sent     = (const int*)d_in[0];
    // d_in[1] transitions: unused by reference
    const float* emb      = (const float*)d_in[2];
    const float* comp_W   = (const float*)d_in[3];
    const float* comp_b   = (const float*)d_in[4];
    const float* sel_W1   = (const float*)d_in[5];
    const float* sel_b1   = (const float*)d_in[6];
    const float* sel_W2   = (const float*)d_in[7];
    const float* sel_b2   = (const float*)d_in[8];
    const float* mlp_W0   = (const float*)d_in[9];
    const float* mlp_b0   = (const float*)d_in[10];
    const float* mlp_W1   = (const float*)d_in[11];
    const float* mlp_b1   = (const float*)d_in[12];
    const float* mlp_Wout = (const float*)d_in[13];
    const float* mlp_bout = (const float*)d_in[14];
    float* outp = (float*)d_out;

    char* p = (char*)d_ws;
    ushort* sh0  = (ushort*)p; p += (size_t)B_ * S_ * D_ * 2;
    ushort* sl0  = (ushort*)p; p += (size_t)B_ * S_ * D_ * 2;
    ushort* sh1  = (ushort*)p; p += (size_t)B_ * S_ * D_ * 2;
    ushort* sl1  = (ushort*)p; p += (size_t)B_ * S_ * D_ * 2;
    ushort* wth  = (ushort*)p; p += (size_t)1280 * 512 * 2;
    ushort* wtl  = (ushort*)p; p += (size_t)1280 * 512 * 2;
    ushort* w1th = (ushort*)p; p += (size_t)128 * 1024 * 2;
    ushort* w1tl = (ushort*)p; p += (size_t)128 * 1024 * 2;
    float*  hid  = (float*)p;  p += (size_t)B_ * 63 * SEL_ * 4;
    float*  coef = (float*)p;  p += (size_t)B_ * 63 * 3 * 4;
    float*  root = (float*)p;  p += (size_t)B_ * D_ * 4;
    float*  h1   = (float*)p;  p += (size_t)B_ * MLPD_ * 4;
    float*  h2   = (float*)p;  p += (size_t)B_ * MLPD_ * 4;

    k_embed<<<dim3(4096), dim3(256), 0, stream>>>(sent, emb, sh0, sl0);
    k_tsplit<<<dim3(20, 8), dim3(256), 0, stream>>>(comp_W, wth, wtl, 512, 1280);
    k_tsplit<<<dim3(2, 16), dim3(256), 0, stream>>>(sel_W1, w1th, w1tl, 1024, 128);

    ushort* shs = sh0; ushort* sls = sl0;
    ushort* shd = sh1; ushort* sld = sl1;
    for (int L = S_; L >= 2; --L) {
        int N = L - 1;
        int M = B_ * N;
        int cdiv = (1048576 + N - 1) / N;
        k_selhid<<<dim3(2 * (M / 64)), dim3(256), 0, stream>>>(shs, sls, w1th, w1tl, sel_b1, hid, N, M, cdiv);
        k_coef<<<dim3(B_), dim3(64), 0, stream>>>(hid, sel_W2, sel_b2, coef, N);
        k_compose<<<dim3(8 * (M / 64)), dim3(256), 0, stream>>>(shs, sls, wth, wtl, comp_b, coef,
                                                                shd, sld, root, N, M, cdiv);
        ushort* th = shs; shs = shd; shd = th;
        ushort* tl = sls; sls = sld; sld = tl;
    }

    k_gemm<1><<<dim3(4, 16), dim3(256), 0, stream>>>(root, mlp_W0, mlp_b0, h1, B_, 512, MLPD_);
    k_gemm<1><<<dim3(4, 16), dim3(256), 0, stream>>>(h1, mlp_W1, mlp_b1, h2, B_, 1024, MLPD_);
    k_gemm<0><<<dim3(4, 1), dim3(256), 0, stream>>>(h2, mlp_Wout, mlp_bout, outp, B_, 1024, CLS_);
}